// Round 5
// baseline (771.730 us; speedup 1.0000x reference)
//
#include <hip/hip_runtime.h>
#include <hip/hip_bf16.h>

constexpr int NN = 100000;
constexpr int NE = 1600000;
constexpr int BSH = 6;                     // bucket = dst >> 6 (64 nodes/bucket)
constexpr int NBK = (NN + 63) >> BSH;      // 1563

typedef __bf16 bf16_t;
typedef bf16_t bf16x8 __attribute__((ext_vector_type(8)));
typedef bf16_t bf16x4 __attribute__((ext_vector_type(4)));
typedef bf16_t bf16x2 __attribute__((ext_vector_type(2)));
typedef float  f32x4  __attribute__((ext_vector_type(4)));

// ---------------- CSR build (bucketed) ----------------

__global__ void zero_i32(int* __restrict__ p, int n) {
  int i = blockIdx.x * blockDim.x + threadIdx.x;
  if (i < n) p[i] = 0;
}

__global__ void bhist_k(const int* __restrict__ dst, int* __restrict__ bhist, int e) {
  int i = blockIdx.x * blockDim.x + threadIdx.x;
  if (i < e) atomicAdd(&bhist[dst[i] >> BSH], 1);
}

constexpr int SB = 256;

__global__ void scan_blk(const int* __restrict__ in, int* __restrict__ incl,
                         int* __restrict__ bsum, int n) {
  __shared__ int sm[SB];
  int i = blockIdx.x * SB + threadIdx.x;
  int v = (i < n) ? in[i] : 0;
  sm[threadIdx.x] = v;
  __syncthreads();
  for (int off = 1; off < SB; off <<= 1) {
    int t = (threadIdx.x >= off) ? sm[threadIdx.x - off] : 0;
    __syncthreads();
    sm[threadIdx.x] += t;
    __syncthreads();
  }
  if (i < n) incl[i] = sm[threadIdx.x];
  if (threadIdx.x == SB - 1) bsum[blockIdx.x] = sm[SB - 1];
}

__global__ void scan_top(int* __restrict__ bsum, int nb) {
  __shared__ int sm[512];
  int t = threadIdx.x;
  int v = (t < nb) ? bsum[t] : 0;
  sm[t] = v;
  __syncthreads();
  for (int off = 1; off < 512; off <<= 1) {
    int u = (t >= off) ? sm[t - off] : 0;
    __syncthreads();
    sm[t] += u;
    __syncthreads();
  }
  if (t < nb) bsum[t] = sm[t] - v;   // exclusive
}

__global__ void scan_add(const int* __restrict__ incl, const int* __restrict__ in,
                         const int* __restrict__ bsum, int* __restrict__ row_off, int n) {
  int i = blockIdx.x * SB + threadIdx.x;
  if (i < n) {
    int off = bsum[blockIdx.x];
    row_off[i] = off + incl[i] - in[i];
    if (i == n - 1) row_off[n] = off + incl[i];
  }
}

// scatter packed (dst,src) into bucket-contiguous ebuf
__global__ void bscatter(const int* __restrict__ src, const int* __restrict__ dst,
                         const int* __restrict__ boff, int* __restrict__ bcur,
                         unsigned long long* __restrict__ ebuf, int e) {
  int i = blockIdx.x * blockDim.x + threadIdx.x;
  if (i >= e) return;
  int d = dst[i], s = src[i];
  int b = d >> BSH;
  int pos = boff[b] + atomicAdd(&bcur[b], 1);
  ebuf[pos] = ((unsigned long long)(unsigned)d << 32) | (unsigned)s;
}

// per-bucket degree histogram (LDS) -> coalesced degi/dinv writes
__global__ __launch_bounds__(256) void bucket_deg(
    const unsigned long long* __restrict__ ebuf, const int* __restrict__ boff,
    int* __restrict__ degi, float* __restrict__ dinv, int n) {
  __shared__ int cnt[64];
  int b = blockIdx.x;
  if (threadIdx.x < 64) cnt[threadIdx.x] = 0;
  __syncthreads();
  int e0 = boff[b], e1 = boff[b + 1];
  for (int e = e0 + threadIdx.x; e < e1; e += 256) {
    int dl = (int)(ebuf[e] >> 32) & 63;
    atomicAdd(&cnt[dl], 1);
  }
  __syncthreads();
  int node = (b << BSH) + threadIdx.x;
  if (threadIdx.x < 64 && node < n) {
    int c = cnt[threadIdx.x];
    degi[node] = c;
    dinv[node] = rsqrtf((float)c + 1.0f);   // +1 self-loop
  }
}

// per-bucket placement into the bucket's contiguous csr region
__global__ __launch_bounds__(256) void place_k(
    const unsigned long long* __restrict__ ebuf, const int* __restrict__ boff,
    const int* __restrict__ row_off, int* __restrict__ csr, int n) {
  __shared__ int ro[64];
  __shared__ int cur[64];
  int b = blockIdx.x;
  int node = (b << BSH) + threadIdx.x;
  if (threadIdx.x < 64) {
    cur[threadIdx.x] = 0;
    ro[threadIdx.x] = (node < n) ? row_off[node] : 0;
  }
  __syncthreads();
  int e0 = boff[b], e1 = boff[b + 1];
  for (int e = e0 + threadIdx.x; e < e1; e += 256) {
    unsigned long long v = ebuf[e];
    int dl = (int)(v >> 32) & 63;
    int s  = (int)(v & 0xffffffffu);
    int slot = ro[dl] + atomicAdd(&cur[dl], 1);
    csr[slot] = s;
  }
}

__global__ void i2f_k(const int* __restrict__ in, float* __restrict__ out, int n) {
  int i = blockIdx.x * blockDim.x + threadIdx.x;
  if (i < n) out[i] = (float)in[i];
}

// f32 -> bf16, 4 at a time
__global__ void f2b_k(const float* __restrict__ in, bf16_t* __restrict__ out, int n4) {
  int i = blockIdx.x * blockDim.x + threadIdx.x;
  if (i < n4) {
    float4 v = ((const float4*)in)[i];
    bf16x4 o;
    o.x = (bf16_t)v.x; o.y = (bf16_t)v.y; o.z = (bf16_t)v.z; o.w = (bf16_t)v.w;
    ((bf16x4*)out)[i] = o;
  }
}

// shuffle W[K][128] f32 into MFMA B-fragment order, bf16:
// Wf[((kt*8 + c)*64 + lane)*8 + j] = W[kt*32 + (lane>>4)*8 + j][c*16 + (lane&15)]
__global__ void wprep(const float* __restrict__ W, bf16_t* __restrict__ Wf, int total) {
  int idx = blockIdx.x * blockDim.x + threadIdx.x;
  if (idx >= total) return;
  int j    = idx & 7;
  int lane = (idx >> 3) & 63;
  int c    = (idx >> 9) & 7;
  int kt   = idx >> 12;
  int k    = kt * 32 + (lane >> 4) * 8 + j;
  int col  = c * 16 + (lane & 15);
  Wf[idx] = (bf16_t)W[(size_t)k * 128 + col];
}

// ---------------- MFMA dense ----------------
// out[N,128] = act( concat(A1[N,K1],A2[N,K2]) @ W + bias )
// 256 threads = 4 waves; each wave: 32 rows x 128 cols. No LDS.
template<int K1, int K2, bool DOELU, bool OUTF32>
__global__ __launch_bounds__(256) void mf_dense(
    const bf16_t* __restrict__ A1, const bf16_t* __restrict__ A2,
    const bf16_t* __restrict__ Wf, const float* __restrict__ bias,
    bf16_t* __restrict__ outb, float* __restrict__ outf, int n)
{
  constexpr int K   = K1 + K2;
  constexpr int NKT = K / 32;
  static_assert(K1 % 32 == 0, "K-step must not straddle A1/A2");

  const int tid  = threadIdx.x;
  const int wv   = tid >> 6;
  const int lane = tid & 63;
  const int r    = lane & 15;
  const int kb   = lane >> 4;
  const int row0 = blockIdx.x * 128 + wv * 32;

  f32x4 acc[2][8];
  #pragma unroll
  for (int i = 0; i < 2; ++i)
    #pragma unroll
    for (int c = 0; c < 8; ++c)
      acc[i][c] = (f32x4){0.f, 0.f, 0.f, 0.f};

  const bf16x8* WfV = (const bf16x8*)Wf;

  #pragma unroll
  for (int kt = 0; kt < NKT; ++kt) {
    const int kofs = kt * 32 + kb * 8;
    bf16x8 a[2];
    #pragma unroll
    for (int i = 0; i < 2; ++i) {
      int row = row0 + i * 16 + r;
      if (row >= n) row = n - 1;
      const bf16_t* ap;
      if (K2 == 0 || kofs < K1) ap = A1 + (size_t)row * K1 + kofs;
      else                      ap = A2 + (size_t)row * K2 + (kofs - K1);
      a[i] = *(const bf16x8*)ap;
    }
    #pragma unroll
    for (int c = 0; c < 8; ++c) {
      bf16x8 b = WfV[(kt * 8 + c) * 64 + lane];
      acc[0][c] = __builtin_amdgcn_mfma_f32_16x16x32_bf16(a[0], b, acc[0][c], 0, 0, 0);
      acc[1][c] = __builtin_amdgcn_mfma_f32_16x16x32_bf16(a[1], b, acc[1][c], 0, 0, 0);
    }
  }

  // C/D layout: col = c*16 + (lane&15), row = rowtile + (lane>>4)*4 + q
  #pragma unroll
  for (int c = 0; c < 8; ++c) {
    const int col = c * 16 + r;
    const float bv = bias ? bias[col] : 0.f;
    #pragma unroll
    for (int i = 0; i < 2; ++i) {
      #pragma unroll
      for (int q = 0; q < 4; ++q) {
        int row = row0 + i * 16 + kb * 4 + q;
        if (row < n) {
          float v = acc[i][c][q] + bv;
          if (DOELU) v = v > 0.f ? v : expm1f(v);
          if (OUTF32) outf[(size_t)row * 128 + col] = v;
          else        outb[(size_t)row * 128 + col] = (bf16_t)v;
        }
      }
    }
  }
}

// ---------------- GCN aggregate: one wave per node, bf16 in/out, fp32 accum ----------------
__global__ __launch_bounds__(256) void gcn_agg_b(
    const int* __restrict__ row_off, const int* __restrict__ csr,
    const float* __restrict__ dinv, const bf16_t* __restrict__ xg,
    const float* __restrict__ bgc, bf16_t* __restrict__ agg, int n)
{
  int w = (int)((blockIdx.x * (unsigned)blockDim.x + threadIdx.x) >> 6);
  int lane = threadIdx.x & 63;
  if (w >= n) return;
  float dd = dinv[w];
  float2 b = ((const float2*)bgc)[lane];
  bf16x2 xv = ((const bf16x2*)(xg + (size_t)w * 128))[lane];
  float s = dd * dd;
  float ax = (float)xv.x * s + b.x;
  float ay = (float)xv.y * s + b.y;
  int e = row_off[w], end = row_off[w + 1];
  for (; e + 4 <= end; e += 4) {
    int s0 = csr[e], s1 = csr[e + 1], s2 = csr[e + 2], s3 = csr[e + 3];
    float n0 = dinv[s0] * dd, n1 = dinv[s1] * dd, n2 = dinv[s2] * dd, n3 = dinv[s3] * dd;
    bf16x2 v0 = ((const bf16x2*)(xg + (size_t)s0 * 128))[lane];
    bf16x2 v1 = ((const bf16x2*)(xg + (size_t)s1 * 128))[lane];
    bf16x2 v2 = ((const bf16x2*)(xg + (size_t)s2 * 128))[lane];
    bf16x2 v3 = ((const bf16x2*)(xg + (size_t)s3 * 128))[lane];
    ax += (float)v0.x * n0 + (float)v1.x * n1 + (float)v2.x * n2 + (float)v3.x * n3;
    ay += (float)v0.y * n0 + (float)v1.y * n1 + (float)v2.y * n2 + (float)v3.y * n3;
  }
  for (; e < end; ++e) {
    int s0 = csr[e];
    float n0 = dinv[s0] * dd;
    bf16x2 v0 = ((const bf16x2*)(xg + (size_t)s0 * 128))[lane];
    ax += (float)v0.x * n0; ay += (float)v0.y * n0;
  }
  bf16x2 o;
  o.x = (bf16_t)ax; o.y = (bf16_t)ay;
  ((bf16x2*)(agg + (size_t)w * 128))[lane] = o;
}

// ---------------- launch ----------------

extern "C" void kernel_launch(void* const* d_in, const int* in_sizes, int n_in,
                              void* d_out, int out_size, void* d_ws, size_t ws_size,
                              hipStream_t stream) {
  (void)in_sizes; (void)n_in; (void)out_size; (void)ws_size;
  const float* feats = (const float*)d_in[0];
  const int*   edges = (const int*)d_in[1];
  const int*   batch = (const int*)d_in[2];
  const float* W1  = (const float*)d_in[3];
  const float* b1  = (const float*)d_in[4];
  const float* W2  = (const float*)d_in[5];
  const float* b2  = (const float*)d_in[6];
  const float* Wgc = (const float*)d_in[7];
  const float* bgc = (const float*)d_in[8];
  const float* Wc  = (const float*)d_in[9];
  const float* bc  = (const float*)d_in[10];
  float* out = (float*)d_out;

  // workspace layout (bf16 activations)
  bf16_t* featsb = (bf16_t*)d_ws;                      // [NN*64]
  bf16_t* h1b    = featsb + (size_t)NN * 64;           // [NN*128]
  bf16_t* h2b    = h1b    + (size_t)NN * 128;          // [NN*128] (nfeats)
  bf16_t* xgb    = h2b    + (size_t)NN * 128;          // [NN*128] (GCN linear out)
  bf16_t* aggb   = xgb    + (size_t)NN * 128;          // [NN*128]
  float*  dinv   = (float*)(aggb + (size_t)NN * 128);  // [NN]
  bf16_t* w1f    = (bf16_t*)(dinv + NN);               // [64*128]
  bf16_t* w2f    = w1f  + 64  * 128;                   // [128*128]
  bf16_t* wgcf   = w2f  + 128 * 128;                   // [192*128]
  bf16_t* wcf    = wgcf + 192 * 128;                   // [256*128]

  // CSR scratch in the FRONT of d_out (dead before final mf_dense writes it)
  int* scr     = (int*)d_out;
  int* csr_src = scr;                   // [NE]
  int* row_off = csr_src + NE;          // [NN+1]
  int* degi    = row_off + NN + 1;      // [NN]
  int* incl    = degi + NN;             // [NN]
  int* bhist   = incl + NN;             // [NBK]
  int* bcur    = bhist + NBK;           // [NBK] (adjacent -> zero both at once)
  int* incl2   = bcur + NBK;            // [NBK]
  int* boff    = incl2 + NBK;           // [NBK+1]
  int* bsum    = boff + NBK + 1;        // [512]
  int* bsum2   = bsum + 512;            // [512]
  unsigned long long* ebuf =
      (unsigned long long*)(((uintptr_t)(bsum2 + 512) + 7) & ~(uintptr_t)7);  // [NE]

  const int* esrc = edges;
  const int* edst = edges + NE;

  const int nbE  = (NE + 255) / 256;
  const int nsc  = (NN + SB - 1) / SB;    // 391
  const int nsc2 = (NBK + SB - 1) / SB;   // 7

  // --- bucketed CSR build ---
  zero_i32<<<(2 * NBK + 255) / 256, 256, 0, stream>>>(bhist, 2 * NBK);
  bhist_k <<<nbE, 256, 0, stream>>>(edst, bhist, NE);
  scan_blk<<<nsc2, SB, 0, stream>>>(bhist, incl2, bsum2, NBK);
  scan_top<<<1, 512, 0, stream>>>(bsum2, nsc2);
  scan_add<<<nsc2, SB, 0, stream>>>(incl2, bhist, bsum2, boff, NBK);
  bscatter<<<nbE, 256, 0, stream>>>(esrc, edst, boff, bcur, ebuf, NE);
  bucket_deg<<<NBK, 256, 0, stream>>>(ebuf, boff, degi, dinv, NN);
  scan_blk<<<nsc, SB, 0, stream>>>(degi, incl, bsum, NN);
  scan_top<<<1, 512, 0, stream>>>(bsum, nsc);
  scan_add<<<nsc, SB, 0, stream>>>(incl, degi, bsum, row_off, NN);
  place_k <<<NBK, 256, 0, stream>>>(ebuf, boff, row_off, csr_src, NN);

  // --- dtype prep ---
  f2b_k<<<(NN * 64 / 4 + 255) / 256, 256, 0, stream>>>(feats, featsb, NN * 64 / 4);
  wprep<<<(64  * 128 + 255) / 256, 256, 0, stream>>>(W1,  w1f,  64  * 128);
  wprep<<<(128 * 128 + 255) / 256, 256, 0, stream>>>(W2,  w2f,  128 * 128);
  wprep<<<(192 * 128 + 255) / 256, 256, 0, stream>>>(Wgc, wgcf, 192 * 128);
  wprep<<<(256 * 128 + 255) / 256, 256, 0, stream>>>(Wc,  wcf,  256 * 128);

  // --- dense chain on MFMA ---
  const int nb = (NN + 127) / 128;
  mf_dense<64, 0, true, false><<<nb, 256, 0, stream>>>(featsb, nullptr, w1f, b1, h1b, nullptr, NN);
  mf_dense<128, 0, true, false><<<nb, 256, 0, stream>>>(h1b, nullptr, w2f, b2, h2b, nullptr, NN);
  mf_dense<128, 64, false, false><<<nb, 256, 0, stream>>>(h2b, featsb, wgcf, nullptr, xgb, nullptr, NN);

  // --- GCN aggregate ---
  long long wthreads = (long long)NN * 64;
  gcn_agg_b<<<(int)((wthreads + 255) / 256), 256, 0, stream>>>(
      row_off, csr_src, dinv, xgb, bgc, aggb, NN);

  // --- output layer (fp32 into d_out, overwrites CSR scratch) ---
  mf_dense<128, 128, true, true><<<nb, 256, 0, stream>>>(h2b, aggb, wcf, bc, nullptr, out, NN);

  // tail outputs: edges and batch, as float
  size_t off = (size_t)NN * 128;
  i2f_k<<<(2 * NE + 255) / 256, 256, 0, stream>>>(edges, out + off, 2 * NE);
  i2f_k<<<(NN + 255) / 256, 256, 0, stream>>>(batch, out + off + (size_t)2 * NE, NN);
}

// Round 6
// 322.677 us; speedup vs baseline: 2.3917x; 2.3917x over previous
//
#include <hip/hip_runtime.h>
#include <hip/hip_bf16.h>

constexpr int NN = 100000;
constexpr int NE = 1600000;

constexpr int SH1  = 9;                      // 512 nodes per bucket
constexpr int NB1  = (NN + 511) >> SH1;      // 196 buckets
constexpr int EB   = 8192;                   // edges per pass-A block
constexpr int NBLK = (NE + EB - 1) / EB;     // 196 blocks
constexpr int NH   = NB1 * NBLK;             // 38416 histogram cells

typedef __bf16 bf16_t;
typedef bf16_t bf16x8 __attribute__((ext_vector_type(8)));
typedef bf16_t bf16x4 __attribute__((ext_vector_type(4)));
typedef bf16_t bf16x2 __attribute__((ext_vector_type(2)));
typedef float  f32x4  __attribute__((ext_vector_type(4)));

// ---------------- generic scan chain ----------------
constexpr int SB = 256;

__global__ void scan_blk(const int* __restrict__ in, int* __restrict__ incl,
                         int* __restrict__ bsum, int n) {
  __shared__ int sm[SB];
  int i = blockIdx.x * SB + threadIdx.x;
  int v = (i < n) ? in[i] : 0;
  sm[threadIdx.x] = v;
  __syncthreads();
  for (int off = 1; off < SB; off <<= 1) {
    int t = (threadIdx.x >= off) ? sm[threadIdx.x - off] : 0;
    __syncthreads();
    sm[threadIdx.x] += t;
    __syncthreads();
  }
  if (i < n) incl[i] = sm[threadIdx.x];
  if (threadIdx.x == SB - 1) bsum[blockIdx.x] = sm[SB - 1];
}

__global__ void scan_top(int* __restrict__ bsum, int nb) {
  __shared__ int sm[512];
  int t = threadIdx.x;
  int v = (t < nb) ? bsum[t] : 0;
  sm[t] = v;
  __syncthreads();
  for (int off = 1; off < 512; off <<= 1) {
    int u = (t >= off) ? sm[t - off] : 0;
    __syncthreads();
    sm[t] += u;
    __syncthreads();
  }
  if (t < nb) bsum[t] = sm[t] - v;   // exclusive
}

__global__ void scan_add(const int* __restrict__ incl, const int* __restrict__ in,
                         const int* __restrict__ bsum, int* __restrict__ outoff, int n) {
  int i = blockIdx.x * SB + threadIdx.x;
  if (i < n) {
    int off = bsum[blockIdx.x];
    outoff[i] = off + incl[i] - in[i];    // exclusive prefix
    if (i == n - 1) outoff[n] = off + incl[i];
  }
}

// ---------------- pass A: block-local histogram + owned-range scatter ----------------

__global__ __launch_bounds__(256) void histA(const int* __restrict__ dst,
                                             int* __restrict__ H, int e) {
  __shared__ int h[NB1];
  for (int i = threadIdx.x; i < NB1; i += 256) h[i] = 0;
  __syncthreads();
  int base = blockIdx.x * EB;
  int end = min(base + EB, e);
  for (int i = base + threadIdx.x; i < end; i += 256)
    atomicAdd(&h[dst[i] >> SH1], 1);
  __syncthreads();
  for (int i = threadIdx.x; i < NB1; i += 256)
    H[i * NBLK + blockIdx.x] = h[i];
}

__global__ void boff_k(const int* __restrict__ Hoff, int* __restrict__ boff) {
  int i = blockIdx.x * blockDim.x + threadIdx.x;
  if (i < NB1) boff[i] = Hoff[i * NBLK];
  if (i == NB1) boff[NB1] = NE;
}

// each block writes its edges into its exclusive (bucket,block) ranges; LDS cursors only
__global__ __launch_bounds__(256) void scatterA(
    const int* __restrict__ src, const int* __restrict__ dst,
    const int* __restrict__ Hoff, unsigned long long* __restrict__ ebuf, int e) {
  __shared__ int cur[NB1];
  for (int i = threadIdx.x; i < NB1; i += 256)
    cur[i] = Hoff[i * NBLK + blockIdx.x];
  __syncthreads();
  int base = blockIdx.x * EB;
  int end = min(base + EB, e);
  for (int i = base + threadIdx.x; i < end; i += 256) {
    int d = dst[i], s = src[i];
    int pos = atomicAdd(&cur[d >> SH1], 1);
    ebuf[pos] = ((unsigned long long)(unsigned)d << 32) | (unsigned)s;
  }
}

// ---------------- pass B: per-bucket degree + placement (single-writer regions) ----------------

__global__ __launch_bounds__(512) void bdeg(const unsigned long long* __restrict__ ebuf,
                                            const int* __restrict__ boff,
                                            int* __restrict__ degi, float* __restrict__ dinv,
                                            int n) {
  __shared__ int cnt[512];
  int b = blockIdx.x;
  cnt[threadIdx.x] = 0;
  __syncthreads();
  int e0 = boff[b], e1 = boff[b + 1];
  for (int e = e0 + (int)threadIdx.x; e < e1; e += 512)
    atomicAdd(&cnt[(int)(ebuf[e] >> 32) & 511], 1);
  __syncthreads();
  int node = (b << SH1) + threadIdx.x;
  if (node < n) {
    int c = cnt[threadIdx.x];
    degi[node] = c;
    dinv[node] = rsqrtf((float)c + 1.0f);   // +1 self-loop
  }
}

__global__ __launch_bounds__(512) void placeB(const unsigned long long* __restrict__ ebuf,
                                              const int* __restrict__ boff,
                                              const int* __restrict__ row_off,
                                              int* __restrict__ csr, int n) {
  __shared__ int cur[512];
  int b = blockIdx.x;
  int node = (b << SH1) + threadIdx.x;
  cur[threadIdx.x] = (node < n) ? row_off[node] : 0;
  __syncthreads();
  int e0 = boff[b], e1 = boff[b + 1];
  for (int e = e0 + (int)threadIdx.x; e < e1; e += 512) {
    unsigned long long v = ebuf[e];
    int dl = (int)(v >> 32) & 511;
    int s  = (int)(v & 0xffffffffu);
    int slot = atomicAdd(&cur[dl], 1);
    csr[slot] = s;
  }
}

// ---------------- misc ----------------

__global__ void i2f_k(const int* __restrict__ in, float* __restrict__ out, int n) {
  int i = blockIdx.x * blockDim.x + threadIdx.x;
  if (i < n) out[i] = (float)in[i];
}

__global__ void f2b_k(const float* __restrict__ in, bf16_t* __restrict__ out, int n4) {
  int i = blockIdx.x * blockDim.x + threadIdx.x;
  if (i < n4) {
    float4 v = ((const float4*)in)[i];
    bf16x4 o;
    o.x = (bf16_t)v.x; o.y = (bf16_t)v.y; o.z = (bf16_t)v.z; o.w = (bf16_t)v.w;
    ((bf16x4*)out)[i] = o;
  }
}

// shuffle W[K][128] f32 into MFMA B-fragment order, bf16:
// Wf[((kt*8 + c)*64 + lane)*8 + j] = W[kt*32 + (lane>>4)*8 + j][c*16 + (lane&15)]
__global__ void wprep(const float* __restrict__ W, bf16_t* __restrict__ Wf, int total) {
  int idx = blockIdx.x * blockDim.x + threadIdx.x;
  if (idx >= total) return;
  int j    = idx & 7;
  int lane = (idx >> 3) & 63;
  int c    = (idx >> 9) & 7;
  int kt   = idx >> 12;
  int k    = kt * 32 + (lane >> 4) * 8 + j;
  int col  = c * 16 + (lane & 15);
  Wf[idx] = (bf16_t)W[(size_t)k * 128 + col];
}

// ---------------- MFMA dense ----------------
// out[N,128] = act( concat(A1[N,K1],A2[N,K2]) @ W + bias )
// 256 threads = 4 waves; each wave: 32 rows x 128 cols. No LDS.
template<int K1, int K2, bool DOELU, bool OUTF32>
__global__ __launch_bounds__(256) void mf_dense(
    const bf16_t* __restrict__ A1, const bf16_t* __restrict__ A2,
    const bf16_t* __restrict__ Wf, const float* __restrict__ bias,
    bf16_t* __restrict__ outb, float* __restrict__ outf, int n)
{
  constexpr int K   = K1 + K2;
  constexpr int NKT = K / 32;
  static_assert(K1 % 32 == 0, "K-step must not straddle A1/A2");

  const int tid  = threadIdx.x;
  const int wv   = tid >> 6;
  const int lane = tid & 63;
  const int r    = lane & 15;
  const int kb   = lane >> 4;
  const int row0 = blockIdx.x * 128 + wv * 32;

  f32x4 acc[2][8];
  #pragma unroll
  for (int i = 0; i < 2; ++i)
    #pragma unroll
    for (int c = 0; c < 8; ++c)
      acc[i][c] = (f32x4){0.f, 0.f, 0.f, 0.f};

  const bf16x8* WfV = (const bf16x8*)Wf;

  #pragma unroll
  for (int kt = 0; kt < NKT; ++kt) {
    const int kofs = kt * 32 + kb * 8;
    bf16x8 a[2];
    #pragma unroll
    for (int i = 0; i < 2; ++i) {
      int row = row0 + i * 16 + r;
      if (row >= n) row = n - 1;
      const bf16_t* ap;
      if (K2 == 0 || kofs < K1) ap = A1 + (size_t)row * K1 + kofs;
      else                      ap = A2 + (size_t)row * K2 + (kofs - K1);
      a[i] = *(const bf16x8*)ap;
    }
    #pragma unroll
    for (int c = 0; c < 8; ++c) {
      bf16x8 b = WfV[(kt * 8 + c) * 64 + lane];
      acc[0][c] = __builtin_amdgcn_mfma_f32_16x16x32_bf16(a[0], b, acc[0][c], 0, 0, 0);
      acc[1][c] = __builtin_amdgcn_mfma_f32_16x16x32_bf16(a[1], b, acc[1][c], 0, 0, 0);
    }
  }

  // C/D layout: col = c*16 + (lane&15), row = rowtile + (lane>>4)*4 + q
  #pragma unroll
  for (int c = 0; c < 8; ++c) {
    const int col = c * 16 + r;
    const float bv = bias ? bias[col] : 0.f;
    #pragma unroll
    for (int i = 0; i < 2; ++i) {
      #pragma unroll
      for (int q = 0; q < 4; ++q) {
        int row = row0 + i * 16 + kb * 4 + q;
        if (row < n) {
          float v = acc[i][c][q] + bv;
          if (DOELU) v = v > 0.f ? v : expm1f(v);
          if (OUTF32) outf[(size_t)row * 128 + col] = v;
          else        outb[(size_t)row * 128 + col] = (bf16_t)v;
        }
      }
    }
  }
}

// ---------------- GCN aggregate: one wave per node, bf16 in/out, fp32 accum ----------------
__global__ __launch_bounds__(256) void gcn_agg_b(
    const int* __restrict__ row_off, const int* __restrict__ csr,
    const float* __restrict__ dinv, const bf16_t* __restrict__ xg,
    const float* __restrict__ bgc, bf16_t* __restrict__ agg, int n)
{
  int w = (int)((blockIdx.x * (unsigned)blockDim.x + threadIdx.x) >> 6);
  int lane = threadIdx.x & 63;
  if (w >= n) return;
  float dd = dinv[w];
  float2 b = ((const float2*)bgc)[lane];
  bf16x2 xv = ((const bf16x2*)(xg + (size_t)w * 128))[lane];
  float s = dd * dd;
  float ax = (float)xv.x * s + b.x;
  float ay = (float)xv.y * s + b.y;
  int e = row_off[w], end = row_off[w + 1];
  for (; e + 4 <= end; e += 4) {
    int s0 = csr[e], s1 = csr[e + 1], s2 = csr[e + 2], s3 = csr[e + 3];
    float n0 = dinv[s0] * dd, n1 = dinv[s1] * dd, n2 = dinv[s2] * dd, n3 = dinv[s3] * dd;
    bf16x2 v0 = ((const bf16x2*)(xg + (size_t)s0 * 128))[lane];
    bf16x2 v1 = ((const bf16x2*)(xg + (size_t)s1 * 128))[lane];
    bf16x2 v2 = ((const bf16x2*)(xg + (size_t)s2 * 128))[lane];
    bf16x2 v3 = ((const bf16x2*)(xg + (size_t)s3 * 128))[lane];
    ax += (float)v0.x * n0 + (float)v1.x * n1 + (float)v2.x * n2 + (float)v3.x * n3;
    ay += (float)v0.y * n0 + (float)v1.y * n1 + (float)v2.y * n2 + (float)v3.y * n3;
  }
  for (; e < end; ++e) {
    int s0 = csr[e];
    float n0 = dinv[s0] * dd;
    bf16x2 v0 = ((const bf16x2*)(xg + (size_t)s0 * 128))[lane];
    ax += (float)v0.x * n0; ay += (float)v0.y * n0;
  }
  bf16x2 o;
  o.x = (bf16_t)ax; o.y = (bf16_t)ay;
  ((bf16x2*)(agg + (size_t)w * 128))[lane] = o;
}

// ---------------- launch ----------------

extern "C" void kernel_launch(void* const* d_in, const int* in_sizes, int n_in,
                              void* d_out, int out_size, void* d_ws, size_t ws_size,
                              hipStream_t stream) {
  (void)in_sizes; (void)n_in; (void)out_size; (void)ws_size;
  const float* feats = (const float*)d_in[0];
  const int*   edges = (const int*)d_in[1];
  const int*   batch = (const int*)d_in[2];
  const float* W1  = (const float*)d_in[3];
  const float* b1  = (const float*)d_in[4];
  const float* W2  = (const float*)d_in[5];
  const float* b2  = (const float*)d_in[6];
  const float* Wgc = (const float*)d_in[7];
  const float* bgc = (const float*)d_in[8];
  const float* Wc  = (const float*)d_in[9];
  const float* bc  = (const float*)d_in[10];
  float* out = (float*)d_out;

  // workspace layout (bf16 activations)
  bf16_t* featsb = (bf16_t*)d_ws;                      // [NN*64]
  bf16_t* h1b    = featsb + (size_t)NN * 64;           // [NN*128]
  bf16_t* h2b    = h1b    + (size_t)NN * 128;          // [NN*128] (nfeats)
  bf16_t* xgb    = h2b    + (size_t)NN * 128;          // [NN*128] (GCN linear out)
  bf16_t* aggb   = xgb    + (size_t)NN * 128;          // [NN*128]
  float*  dinv   = (float*)(aggb + (size_t)NN * 128);  // [NN]
  bf16_t* w1f    = (bf16_t*)(dinv + NN);               // [64*128]
  bf16_t* w2f    = w1f  + 64  * 128;                   // [128*128]
  bf16_t* wgcf   = w2f  + 128 * 128;                   // [192*128]
  bf16_t* wcf    = wgcf + 192 * 128;                   // [256*128]

  // scratch in the FRONT of d_out (dead before final mf_dense writes it)
  int* scr     = (int*)d_out;
  int* csr_src = scr;                   // [NE]
  int* row_off = csr_src + NE;          // [NN+1]
  int* degi    = row_off + NN + 1;      // [NN]
  int* incl    = degi + NN;             // [NN]
  int* H       = incl + NN;             // [NH]
  int* Hincl   = H + NH;                // [NH]
  int* Hoff    = Hincl + NH;            // [NH+1]
  int* boff    = Hoff + NH + 1;         // [NB1+1]
  int* bsum    = boff + NB1 + 1;        // [512]
  int* bsum2   = bsum + 512;            // [512]
  unsigned long long* ebuf =
      (unsigned long long*)(((uintptr_t)(bsum2 + 512) + 7) & ~(uintptr_t)7);  // [NE]

  const int* esrc = edges;
  const int* edst = edges + NE;

  const int nscN = (NN + SB - 1) / SB;   // 391
  const int nscH = (NH + SB - 1) / SB;   // 151

  // --- pass A: block-owned bucket sort of edges ---
  histA   <<<NBLK, 256, 0, stream>>>(edst, H, NE);
  scan_blk<<<nscH, SB, 0, stream>>>(H, Hincl, bsum2, NH);
  scan_top<<<1, 512, 0, stream>>>(bsum2, nscH);
  scan_add<<<nscH, SB, 0, stream>>>(Hincl, H, bsum2, Hoff, NH);
  boff_k  <<<1, 256, 0, stream>>>(Hoff, boff);
  scatterA<<<NBLK, 256, 0, stream>>>(esrc, edst, Hoff, ebuf, NE);

  // --- pass B: per-bucket degree, row offsets, placement ---
  bdeg    <<<NB1, 512, 0, stream>>>(ebuf, boff, degi, dinv, NN);
  scan_blk<<<nscN, SB, 0, stream>>>(degi, incl, bsum, NN);
  scan_top<<<1, 512, 0, stream>>>(bsum, nscN);
  scan_add<<<nscN, SB, 0, stream>>>(incl, degi, bsum, row_off, NN);
  placeB  <<<NB1, 512, 0, stream>>>(ebuf, boff, row_off, csr_src, NN);

  // --- dtype prep ---
  f2b_k<<<(NN * 64 / 4 + 255) / 256, 256, 0, stream>>>(feats, featsb, NN * 64 / 4);
  wprep<<<(64  * 128 + 255) / 256, 256, 0, stream>>>(W1,  w1f,  64  * 128);
  wprep<<<(128 * 128 + 255) / 256, 256, 0, stream>>>(W2,  w2f,  128 * 128);
  wprep<<<(192 * 128 + 255) / 256, 256, 0, stream>>>(Wgc, wgcf, 192 * 128);
  wprep<<<(256 * 128 + 255) / 256, 256, 0, stream>>>(Wc,  wcf,  256 * 128);

  // --- dense chain on MFMA ---
  const int nb = (NN + 127) / 128;
  mf_dense<64, 0, true, false><<<nb, 256, 0, stream>>>(featsb, nullptr, w1f, b1, h1b, nullptr, NN);
  mf_dense<128, 0, true, false><<<nb, 256, 0, stream>>>(h1b, nullptr, w2f, b2, h2b, nullptr, NN);
  mf_dense<128, 64, false, false><<<nb, 256, 0, stream>>>(h2b, featsb, wgcf, nullptr, xgb, nullptr, NN);

  // --- GCN aggregate ---
  long long wthreads = (long long)NN * 64;
  gcn_agg_b<<<(int)((wthreads + 255) / 256), 256, 0, stream>>>(
      row_off, csr_src, dinv, xgb, bgc, aggb, NN);

  // --- output layer (fp32 into d_out, overwrites scratch) ---
  mf_dense<128, 128, true, true><<<nb, 256, 0, stream>>>(h2b, aggb, wcf, bc, nullptr, out, NN);

  // tail outputs: edges and batch, as float
  size_t off = (size_t)NN * 128;
  i2f_k<<<(2 * NE + 255) / 256, 256, 0, stream>>>(edges, out + off, 2 * NE);
  i2f_k<<<(NN + 255) / 256, 256, 0, stream>>>(batch, out + off + (size_t)2 * NE, NN);
}

// Round 7
// 322.494 us; speedup vs baseline: 2.3930x; 1.0006x over previous
//
#include <hip/hip_runtime.h>
#include <hip/hip_bf16.h>

constexpr int NN = 100000;
constexpr int NE = 1600000;

constexpr int SH1  = 9;                      // 512 nodes per bucket
constexpr int NB1  = (NN + 511) >> SH1;      // 196 buckets
constexpr int EB   = 8192;                   // edges per pass-A block
constexpr int NBLK = (NE + EB - 1) / EB;     // 196 blocks
constexpr int NH   = NB1 * NBLK;             // 38416 histogram cells

typedef __bf16 bf16_t;
typedef bf16_t bf16x8 __attribute__((ext_vector_type(8)));
typedef bf16_t bf16x4 __attribute__((ext_vector_type(4)));
typedef bf16_t bf16x2 __attribute__((ext_vector_type(2)));
typedef float  f32x4  __attribute__((ext_vector_type(4)));

// ---------------- generic scan chain ----------------
constexpr int SB = 256;

__global__ void scan_blk(const int* __restrict__ in, int* __restrict__ incl,
                         int* __restrict__ bsum, int n) {
  __shared__ int sm[SB];
  int i = blockIdx.x * SB + threadIdx.x;
  int v = (i < n) ? in[i] : 0;
  sm[threadIdx.x] = v;
  __syncthreads();
  for (int off = 1; off < SB; off <<= 1) {
    int t = (threadIdx.x >= off) ? sm[threadIdx.x - off] : 0;
    __syncthreads();
    sm[threadIdx.x] += t;
    __syncthreads();
  }
  if (i < n) incl[i] = sm[threadIdx.x];
  if (threadIdx.x == SB - 1) bsum[blockIdx.x] = sm[SB - 1];
}

__global__ void scan_top(int* __restrict__ bsum, int nb) {
  __shared__ int sm[512];
  int t = threadIdx.x;
  int v = (t < nb) ? bsum[t] : 0;
  sm[t] = v;
  __syncthreads();
  for (int off = 1; off < 512; off <<= 1) {
    int u = (t >= off) ? sm[t - off] : 0;
    __syncthreads();
    sm[t] += u;
    __syncthreads();
  }
  if (t < nb) bsum[t] = sm[t] - v;   // exclusive
}

__global__ void scan_add(const int* __restrict__ incl, const int* __restrict__ in,
                         const int* __restrict__ bsum, int* __restrict__ outoff, int n) {
  int i = blockIdx.x * SB + threadIdx.x;
  if (i < n) {
    int off = bsum[blockIdx.x];
    outoff[i] = off + incl[i] - in[i];    // exclusive prefix
    if (i == n - 1) outoff[n] = off + incl[i];
  }
}

// ---------------- pass A: block-local histogram + owned-range scatter ----------------

__global__ __launch_bounds__(256) void histA(const int* __restrict__ dst,
                                             int* __restrict__ H, int e) {
  __shared__ int h[NB1];
  for (int i = threadIdx.x; i < NB1; i += 256) h[i] = 0;
  __syncthreads();
  int base = blockIdx.x * EB;
  int end = min(base + EB, e);
  for (int i = base + threadIdx.x; i < end; i += 256)
    atomicAdd(&h[dst[i] >> SH1], 1);
  __syncthreads();
  for (int i = threadIdx.x; i < NB1; i += 256)
    H[i * NBLK + blockIdx.x] = h[i];
}

__global__ void boff_k(const int* __restrict__ Hoff, int* __restrict__ boff) {
  int i = blockIdx.x * blockDim.x + threadIdx.x;
  if (i < NB1) boff[i] = Hoff[i * NBLK];
  if (i == NB1) boff[NB1] = NE;
}

// each block writes its edges into its exclusive (bucket,block) ranges; LDS cursors only
__global__ __launch_bounds__(256) void scatterA(
    const int* __restrict__ src, const int* __restrict__ dst,
    const int* __restrict__ Hoff, unsigned long long* __restrict__ ebuf, int e) {
  __shared__ int cur[NB1];
  for (int i = threadIdx.x; i < NB1; i += 256)
    cur[i] = Hoff[i * NBLK + blockIdx.x];
  __syncthreads();
  int base = blockIdx.x * EB;
  int end = min(base + EB, e);
  for (int i = base + threadIdx.x; i < end; i += 256) {
    int d = dst[i], s = src[i];
    int pos = atomicAdd(&cur[d >> SH1], 1);
    ebuf[pos] = ((unsigned long long)(unsigned)d << 32) | (unsigned)s;
  }
}

// ---------------- pass B: per-bucket degree + placement (single-writer regions) ----------------

__global__ __launch_bounds__(512) void bdeg(const unsigned long long* __restrict__ ebuf,
                                            const int* __restrict__ boff,
                                            int* __restrict__ degi, float* __restrict__ dinv,
                                            int n) {
  __shared__ int cnt[512];
  int b = blockIdx.x;
  cnt[threadIdx.x] = 0;
  __syncthreads();
  int e0 = boff[b], e1 = boff[b + 1];
  for (int e = e0 + (int)threadIdx.x; e < e1; e += 512)
    atomicAdd(&cnt[(int)(ebuf[e] >> 32) & 511], 1);
  __syncthreads();
  int node = (b << SH1) + threadIdx.x;
  if (node < n) {
    int c = cnt[threadIdx.x];
    degi[node] = c;
    dinv[node] = rsqrtf((float)c + 1.0f);   // +1 self-loop
  }
}

__global__ __launch_bounds__(512) void placeB(const unsigned long long* __restrict__ ebuf,
                                              const int* __restrict__ boff,
                                              const int* __restrict__ row_off,
                                              int* __restrict__ csr, int n) {
  __shared__ int cur[512];
  int b = blockIdx.x;
  int node = (b << SH1) + threadIdx.x;
  cur[threadIdx.x] = (node < n) ? row_off[node] : 0;
  __syncthreads();
  int e0 = boff[b], e1 = boff[b + 1];
  for (int e = e0 + (int)threadIdx.x; e < e1; e += 512) {
    unsigned long long v = ebuf[e];
    int dl = (int)(v >> 32) & 511;
    int s  = (int)(v & 0xffffffffu);
    int slot = atomicAdd(&cur[dl], 1);
    csr[slot] = s;
  }
}

// ---------------- misc ----------------

__global__ void i2f_k(const int* __restrict__ in, float* __restrict__ out, int n) {
  int i = blockIdx.x * blockDim.x + threadIdx.x;
  if (i < n) out[i] = (float)in[i];
}

__global__ void f2b_k(const float* __restrict__ in, bf16_t* __restrict__ out, int n4) {
  int i = blockIdx.x * blockDim.x + threadIdx.x;
  if (i < n4) {
    float4 v = ((const float4*)in)[i];
    bf16x4 o;
    o.x = (bf16_t)v.x; o.y = (bf16_t)v.y; o.z = (bf16_t)v.z; o.w = (bf16_t)v.w;
    ((bf16x4*)out)[i] = o;
  }
}

// shuffle W[K][128] f32 into MFMA B-fragment order, bf16:
// Wf[((kt*8 + c)*64 + lane)*8 + j] = W[kt*32 + (lane>>4)*8 + j][c*16 + (lane&15)]
__global__ void wprep(const float* __restrict__ W, bf16_t* __restrict__ Wf, int total) {
  int idx = blockIdx.x * blockDim.x + threadIdx.x;
  if (idx >= total) return;
  int j    = idx & 7;
  int lane = (idx >> 3) & 63;
  int c    = (idx >> 9) & 7;
  int kt   = idx >> 12;
  int k    = kt * 32 + (lane >> 4) * 8 + j;
  int col  = c * 16 + (lane & 15);
  Wf[idx] = (bf16_t)W[(size_t)k * 128 + col];
}

// ---------------- MFMA dense ----------------
// out[N,128] = act( concat(A1[N,K1],A2[N,K2]) @ W + bias ) [ * dinv[row] if SCALE ]
// 256 threads = 4 waves; each wave: 32 rows x 128 cols. No LDS.
template<int K1, int K2, bool DOELU, bool OUTF32, bool SCALE>
__global__ __launch_bounds__(256) void mf_dense(
    const bf16_t* __restrict__ A1, const bf16_t* __restrict__ A2,
    const bf16_t* __restrict__ Wf, const float* __restrict__ bias,
    const float* __restrict__ dinv_g,
    bf16_t* __restrict__ outb, float* __restrict__ outf, int n)
{
  constexpr int K   = K1 + K2;
  constexpr int NKT = K / 32;
  static_assert(K1 % 32 == 0, "K-step must not straddle A1/A2");

  const int tid  = threadIdx.x;
  const int wv   = tid >> 6;
  const int lane = tid & 63;
  const int r    = lane & 15;
  const int kb   = lane >> 4;
  const int row0 = blockIdx.x * 128 + wv * 32;

  f32x4 acc[2][8];
  #pragma unroll
  for (int i = 0; i < 2; ++i)
    #pragma unroll
    for (int c = 0; c < 8; ++c)
      acc[i][c] = (f32x4){0.f, 0.f, 0.f, 0.f};

  const bf16x8* WfV = (const bf16x8*)Wf;

  #pragma unroll
  for (int kt = 0; kt < NKT; ++kt) {
    const int kofs = kt * 32 + kb * 8;
    bf16x8 a[2];
    #pragma unroll
    for (int i = 0; i < 2; ++i) {
      int row = row0 + i * 16 + r;
      if (row >= n) row = n - 1;
      const bf16_t* ap;
      if (K2 == 0 || kofs < K1) ap = A1 + (size_t)row * K1 + kofs;
      else                      ap = A2 + (size_t)row * K2 + (kofs - K1);
      a[i] = *(const bf16x8*)ap;
    }
    #pragma unroll
    for (int c = 0; c < 8; ++c) {
      bf16x8 b = WfV[(kt * 8 + c) * 64 + lane];
      acc[0][c] = __builtin_amdgcn_mfma_f32_16x16x32_bf16(a[0], b, acc[0][c], 0, 0, 0);
      acc[1][c] = __builtin_amdgcn_mfma_f32_16x16x32_bf16(a[1], b, acc[1][c], 0, 0, 0);
    }
  }

  // C/D layout: col = c*16 + (lane&15), row = rowtile + (lane>>4)*4 + q
  #pragma unroll
  for (int c = 0; c < 8; ++c) {
    const int col = c * 16 + r;
    const float bv = bias ? bias[col] : 0.f;
    #pragma unroll
    for (int i = 0; i < 2; ++i) {
      #pragma unroll
      for (int q = 0; q < 4; ++q) {
        int row = row0 + i * 16 + kb * 4 + q;
        if (row < n) {
          float v = acc[i][c][q] + bv;
          if (DOELU) v = v > 0.f ? v : expm1f(v);
          if (SCALE) v *= dinv_g[row];
          if (OUTF32) outf[(size_t)row * 128 + col] = v;
          else        outb[(size_t)row * 128 + col] = (bf16_t)v;
        }
      }
    }
  }
}

// ---------------- GCN aggregate v2 ----------------
// xs[s] = xg[s]*dinv[s] (pre-scaled). agg[d] = sum_{s in N(d)} xs[s] + xs[d]*dinv[d] + bgc.
// One wave per node; lanes 0-31 take even edges, 32-63 odd edges; bf16x4 (8B) per lane;
// halves combined at the end with shfl_xor(32). 8 row-loads in flight in the fast path.
__global__ __launch_bounds__(256) void gcn_agg2(
    const int* __restrict__ row_off, const int* __restrict__ csr,
    const float* __restrict__ dinv, const bf16_t* __restrict__ xs,
    const float* __restrict__ bgc, bf16_t* __restrict__ agg, int n)
{
  int w = (int)((blockIdx.x * (unsigned)blockDim.x + threadIdx.x) >> 6);
  if (w >= n) return;
  const int lane = threadIdx.x & 63;
  const int h  = lane >> 5;     // edge parity handled by this half-wave
  const int li = lane & 31;     // feature group: cols 4*li .. 4*li+3

  f32x4 acc;
  if (h == 0) {
    // self-loop term: xs[w] * dinv[w]
    float dd = dinv[w];
    bf16x4 sv = ((const bf16x4*)(xs + (size_t)w * 128))[li];
    acc[0] = (float)sv[0] * dd; acc[1] = (float)sv[1] * dd;
    acc[2] = (float)sv[2] * dd; acc[3] = (float)sv[3] * dd;
  } else {
    acc = ((const f32x4*)bgc)[li];
  }

  const int e0 = row_off[w], e1 = row_off[w + 1];
  int e = e0;
  for (; e + 8 <= e1; e += 8) {
    #pragma unroll
    for (int u = 0; u < 4; ++u) {
      int s = csr[e + 2 * u + h];
      bf16x4 v = ((const bf16x4*)(xs + (size_t)s * 128))[li];
      acc[0] += (float)v[0]; acc[1] += (float)v[1];
      acc[2] += (float)v[2]; acc[3] += (float)v[3];
    }
  }
  for (; e < e1; e += 2) {
    int idx = e + h;
    int cidx = idx < e1 ? idx : e1 - 1;
    int s = csr[cidx];
    float coef = idx < e1 ? 1.f : 0.f;
    bf16x4 v = ((const bf16x4*)(xs + (size_t)s * 128))[li];
    acc[0] += (float)v[0] * coef; acc[1] += (float)v[1] * coef;
    acc[2] += (float)v[2] * coef; acc[3] += (float)v[3] * coef;
  }

  // combine even/odd halves
  #pragma unroll
  for (int j = 0; j < 4; ++j) acc[j] += __shfl_xor(acc[j], 32);

  if (h == 0) {
    bf16x4 o;
    o[0] = (bf16_t)acc[0]; o[1] = (bf16_t)acc[1];
    o[2] = (bf16_t)acc[2]; o[3] = (bf16_t)acc[3];
    ((bf16x4*)(agg + (size_t)w * 128))[li] = o;
  }
}

// ---------------- launch ----------------

extern "C" void kernel_launch(void* const* d_in, const int* in_sizes, int n_in,
                              void* d_out, int out_size, void* d_ws, size_t ws_size,
                              hipStream_t stream) {
  (void)in_sizes; (void)n_in; (void)out_size; (void)ws_size;
  const float* feats = (const float*)d_in[0];
  const int*   edges = (const int*)d_in[1];
  const int*   batch = (const int*)d_in[2];
  const float* W1  = (const float*)d_in[3];
  const float* b1  = (const float*)d_in[4];
  const float* W2  = (const float*)d_in[5];
  const float* b2  = (const float*)d_in[6];
  const float* Wgc = (const float*)d_in[7];
  const float* bgc = (const float*)d_in[8];
  const float* Wc  = (const float*)d_in[9];
  const float* bc  = (const float*)d_in[10];
  float* out = (float*)d_out;

  // workspace layout (bf16 activations)
  bf16_t* featsb = (bf16_t*)d_ws;                      // [NN*64]
  bf16_t* h1b    = featsb + (size_t)NN * 64;           // [NN*128]
  bf16_t* h2b    = h1b    + (size_t)NN * 128;          // [NN*128] (nfeats)
  bf16_t* xsb    = h2b    + (size_t)NN * 128;          // [NN*128] (GCN linear out, pre-scaled by dinv)
  bf16_t* aggb   = xsb    + (size_t)NN * 128;          // [NN*128]
  float*  dinv   = (float*)(aggb + (size_t)NN * 128);  // [NN]
  bf16_t* w1f    = (bf16_t*)(dinv + NN);               // [64*128]
  bf16_t* w2f    = w1f  + 64  * 128;                   // [128*128]
  bf16_t* wgcf   = w2f  + 128 * 128;                   // [192*128]
  bf16_t* wcf    = wgcf + 192 * 128;                   // [256*128]

  // scratch in the FRONT of d_out (dead before final mf_dense writes it)
  int* scr     = (int*)d_out;
  int* csr_src = scr;                   // [NE]
  int* row_off = csr_src + NE;          // [NN+1]
  int* degi    = row_off + NN + 1;      // [NN]
  int* incl    = degi + NN;             // [NN]
  int* H       = incl + NN;             // [NH]
  int* Hincl   = H + NH;                // [NH]
  int* Hoff    = Hincl + NH;            // [NH+1]
  int* boff    = Hoff + NH + 1;         // [NB1+1]
  int* bsum    = boff + NB1 + 1;        // [512]
  int* bsum2   = bsum + 512;            // [512]
  unsigned long long* ebuf =
      (unsigned long long*)(((uintptr_t)(bsum2 + 512) + 7) & ~(uintptr_t)7);  // [NE]

  const int* esrc = edges;
  const int* edst = edges + NE;

  const int nscN = (NN + SB - 1) / SB;   // 391
  const int nscH = (NH + SB - 1) / SB;   // 151

  // --- pass A: block-owned bucket sort of edges ---
  histA   <<<NBLK, 256, 0, stream>>>(edst, H, NE);
  scan_blk<<<nscH, SB, 0, stream>>>(H, Hincl, bsum2, NH);
  scan_top<<<1, 512, 0, stream>>>(bsum2, nscH);
  scan_add<<<nscH, SB, 0, stream>>>(Hincl, H, bsum2, Hoff, NH);
  boff_k  <<<1, 256, 0, stream>>>(Hoff, boff);
  scatterA<<<NBLK, 256, 0, stream>>>(esrc, edst, Hoff, ebuf, NE);

  // --- pass B: per-bucket degree, row offsets, placement ---
  bdeg    <<<NB1, 512, 0, stream>>>(ebuf, boff, degi, dinv, NN);
  scan_blk<<<nscN, SB, 0, stream>>>(degi, incl, bsum, NN);
  scan_top<<<1, 512, 0, stream>>>(bsum, nscN);
  scan_add<<<nscN, SB, 0, stream>>>(incl, degi, bsum, row_off, NN);
  placeB  <<<NB1, 512, 0, stream>>>(ebuf, boff, row_off, csr_src, NN);

  // --- dtype prep ---
  f2b_k<<<(NN * 64 / 4 + 255) / 256, 256, 0, stream>>>(feats, featsb, NN * 64 / 4);
  wprep<<<(64  * 128 + 255) / 256, 256, 0, stream>>>(W1,  w1f,  64  * 128);
  wprep<<<(128 * 128 + 255) / 256, 256, 0, stream>>>(W2,  w2f,  128 * 128);
  wprep<<<(192 * 128 + 255) / 256, 256, 0, stream>>>(Wgc, wgcf, 192 * 128);
  wprep<<<(256 * 128 + 255) / 256, 256, 0, stream>>>(Wc,  wcf,  256 * 128);

  // --- dense chain on MFMA ---
  const int nb = (NN + 127) / 128;
  mf_dense<64, 0, true, false, false><<<nb, 256, 0, stream>>>(
      featsb, nullptr, w1f, b1, nullptr, h1b, nullptr, NN);
  mf_dense<128, 0, true, false, false><<<nb, 256, 0, stream>>>(
      h1b, nullptr, w2f, b2, nullptr, h2b, nullptr, NN);
  // GCN linear layer: pre-scale each output row by dinv[row] (frees per-edge dinv gather)
  mf_dense<128, 64, false, false, true><<<nb, 256, 0, stream>>>(
      h2b, featsb, wgcf, nullptr, dinv, xsb, nullptr, NN);

  // --- GCN aggregate ---
  long long wthreads = (long long)NN * 64;
  gcn_agg2<<<(int)((wthreads + 255) / 256), 256, 0, stream>>>(
      row_off, csr_src, dinv, xsb, bgc, aggb, NN);

  // --- output layer (fp32 into d_out, overwrites scratch) ---
  mf_dense<128, 128, true, true, false><<<nb, 256, 0, stream>>>(
      h2b, aggb, wcf, bc, nullptr, nullptr, out, NN);

  // tail outputs: edges and batch, as float
  size_t off = (size_t)NN * 128;
  i2f_k<<<(2 * NE + 255) / 256, 256, 0, stream>>>(edges, out + off, 2 * NE);
  i2f_k<<<(NN + 255) / 256, 256, 0, stream>>>(batch, out + off + (size_t)2 * NE, NN);
}

// Round 8
// 283.878 us; speedup vs baseline: 2.7185x; 1.1360x over previous
//
#include <hip/hip_runtime.h>
#include <hip/hip_bf16.h>

constexpr int NN = 100000;
constexpr int NE = 1600000;

constexpr int SH1  = 9;                      // 512 nodes per bucket
constexpr int NB1  = (NN + 511) >> SH1;      // 196 buckets
constexpr int EB   = 8192;                   // edges per pass-A block
constexpr int NBLK = (NE + EB - 1) / EB;     // 196 blocks
constexpr int NH   = NB1 * NBLK;             // 38416 histogram cells

typedef __bf16 bf16_t;
typedef bf16_t bf16x8 __attribute__((ext_vector_type(8)));
typedef bf16_t bf16x4 __attribute__((ext_vector_type(4)));
typedef float  f32x4  __attribute__((ext_vector_type(4)));

// ---------------- generic scan chain (used for H only) ----------------
constexpr int SB = 256;

__global__ void scan_blk(const int* __restrict__ in, int* __restrict__ incl,
                         int* __restrict__ bsum, int n) {
  __shared__ int sm[SB];
  int i = blockIdx.x * SB + threadIdx.x;
  int v = (i < n) ? in[i] : 0;
  sm[threadIdx.x] = v;
  __syncthreads();
  for (int off = 1; off < SB; off <<= 1) {
    int t = (threadIdx.x >= off) ? sm[threadIdx.x - off] : 0;
    __syncthreads();
    sm[threadIdx.x] += t;
    __syncthreads();
  }
  if (i < n) incl[i] = sm[threadIdx.x];
  if (threadIdx.x == SB - 1) bsum[blockIdx.x] = sm[SB - 1];
}

__global__ void scan_top(int* __restrict__ bsum, int nb) {
  __shared__ int sm[512];
  int t = threadIdx.x;
  int v = (t < nb) ? bsum[t] : 0;
  sm[t] = v;
  __syncthreads();
  for (int off = 1; off < 512; off <<= 1) {
    int u = (t >= off) ? sm[t - off] : 0;
    __syncthreads();
    sm[t] += u;
    __syncthreads();
  }
  if (t < nb) bsum[t] = sm[t] - v;   // exclusive
}

__global__ void scan_add(const int* __restrict__ incl, const int* __restrict__ in,
                         const int* __restrict__ bsum, int* __restrict__ outoff, int n) {
  int i = blockIdx.x * SB + threadIdx.x;
  if (i < n) {
    int off = bsum[blockIdx.x];
    outoff[i] = off + incl[i] - in[i];    // exclusive prefix
    if (i == n - 1) outoff[n] = off + incl[i];
  }
}

// ---------------- pass A: block-local histogram + owned-range scatter ----------------

__global__ __launch_bounds__(256) void histA(const int* __restrict__ dst,
                                             int* __restrict__ H, int e) {
  __shared__ int h[NB1];
  for (int i = threadIdx.x; i < NB1; i += 256) h[i] = 0;
  __syncthreads();
  int base = blockIdx.x * EB;
  int end = min(base + EB, e);
  for (int i = base + threadIdx.x; i < end; i += 256)
    atomicAdd(&h[dst[i] >> SH1], 1);
  __syncthreads();
  for (int i = threadIdx.x; i < NB1; i += 256)
    H[i * NBLK + blockIdx.x] = h[i];
}

__global__ void boff_k(const int* __restrict__ Hoff, int* __restrict__ boff) {
  int i = blockIdx.x * blockDim.x + threadIdx.x;
  if (i < NB1) boff[i] = Hoff[i * NBLK];
  if (i == NB1) boff[NB1] = NE;
}

// each block writes its edges into its exclusive (bucket,block) ranges; LDS cursors only
__global__ __launch_bounds__(256) void scatterA(
    const int* __restrict__ src, const int* __restrict__ dst,
    const int* __restrict__ Hoff, unsigned long long* __restrict__ ebuf, int e) {
  __shared__ int cur[NB1];
  for (int i = threadIdx.x; i < NB1; i += 256)
    cur[i] = Hoff[i * NBLK + blockIdx.x];
  __syncthreads();
  int base = blockIdx.x * EB;
  int end = min(base + EB, e);
  for (int i = base + threadIdx.x; i < end; i += 256) {
    int d = dst[i], s = src[i];
    int pos = atomicAdd(&cur[d >> SH1], 1);
    ebuf[pos] = ((unsigned long long)(unsigned)d << 32) | (unsigned)s;
  }
}

// ---------------- pass B fused: per-bucket degree + scan + row_off + dinv + placement ----------------

__global__ __launch_bounds__(512) void bfin(const unsigned long long* __restrict__ ebuf,
                                            const int* __restrict__ boff,
                                            int* __restrict__ row_off, float* __restrict__ dinv,
                                            int* __restrict__ csr, int n) {
  __shared__ int cnt[512];
  __shared__ int loc[512];
  const int tid = threadIdx.x;
  const int b = blockIdx.x;
  cnt[tid] = 0;
  __syncthreads();
  const int e0 = boff[b], e1 = boff[b + 1];
  for (int e = e0 + tid; e < e1; e += 512)
    atomicAdd(&cnt[(int)(ebuf[e] >> 32) & 511], 1);
  __syncthreads();
  // inclusive scan over 512
  loc[tid] = cnt[tid];
  __syncthreads();
  for (int off = 1; off < 512; off <<= 1) {
    int t = (tid >= off) ? loc[tid - off] : 0;
    __syncthreads();
    loc[tid] += t;
    __syncthreads();
  }
  const int excl = loc[tid] - cnt[tid];
  const int node = (b << SH1) + tid;
  if (node < n) {
    row_off[node] = boff[b] + excl;
    dinv[node] = rsqrtf((float)cnt[tid] + 1.0f);   // +1 self-loop
  }
  if (b == NB1 - 1 && tid == 0) row_off[n] = NE;
  // reuse cnt[] as cursors
  cnt[tid] = boff[b] + excl;
  __syncthreads();
  for (int e = e0 + tid; e < e1; e += 512) {
    unsigned long long v = ebuf[e];
    int dl = (int)(v >> 32) & 511;
    int s  = (int)(v & 0xffffffffu);
    int slot = atomicAdd(&cnt[dl], 1);
    csr[slot] = s;
  }
}

// ---------------- misc ----------------

__global__ void i2f_k(const int* __restrict__ in, float* __restrict__ out, int n) {
  int i = blockIdx.x * blockDim.x + threadIdx.x;
  if (i < n) out[i] = (float)in[i];
}

// all four weight shuffles in one launch. Wf regions: W1[0,8192) W2[8192,24576)
// Wgc[24576,49152) Wc[49152,81920). grid = 320*256 = 81920 exactly.
__global__ void wprep4(const float* __restrict__ W1, const float* __restrict__ W2,
                       const float* __restrict__ Wgc, const float* __restrict__ Wc,
                       bf16_t* __restrict__ Wf) {
  int idx = blockIdx.x * blockDim.x + threadIdx.x;
  const float* W; int base;
  if      (idx < 8192)  { W = W1;  base = 0; }
  else if (idx < 24576) { W = W2;  base = 8192; }
  else if (idx < 49152) { W = Wgc; base = 24576; }
  else                  { W = Wc;  base = 49152; }
  int il   = idx - base;
  int j    = il & 7;
  int lane = (il >> 3) & 63;
  int c    = (il >> 9) & 7;
  int kt   = il >> 12;
  int k    = kt * 32 + (lane >> 4) * 8 + j;
  int col  = c * 16 + (lane & 15);
  Wf[idx] = (bf16_t)W[(size_t)k * 128 + col];
}

// ---------------- fused dense layers 1+2 ----------------
// h2 = elu( elu(feats @ W1 + b1) @ W2 + b2 ); feats read as f32; h1 staged in
// XOR-swizzled LDS (2-way bank alias = free). Each wave owns its 32 rows end-to-end.
__global__ __launch_bounds__(256) void mf_dense12(
    const float* __restrict__ A, const bf16_t* __restrict__ W1f, const float* __restrict__ b1,
    const bf16_t* __restrict__ W2f, const float* __restrict__ b2,
    bf16_t* __restrict__ outb, int n)
{
  __shared__ __align__(16) char h1s[128 * 256];   // 128 rows x 128 bf16 (256 B/row)
  const int tid  = threadIdx.x;
  const int wv   = tid >> 6;
  const int lane = tid & 63;
  const int r    = lane & 15;
  const int kb   = lane >> 4;
  const int row0 = blockIdx.x * 128 + wv * 32;

  const bf16x8* W1V = (const bf16x8*)W1f;
  const bf16x8* W2V = (const bf16x8*)W2f;

  // ---- phase 1: K=64, A = f32 feats ----
  f32x4 acc[2][8];
  #pragma unroll
  for (int i = 0; i < 2; ++i)
    #pragma unroll
    for (int c = 0; c < 8; ++c) acc[i][c] = (f32x4){0.f, 0.f, 0.f, 0.f};

  #pragma unroll
  for (int kt = 0; kt < 2; ++kt) {
    const int kofs = kt * 32 + kb * 8;
    bf16x8 a[2];
    #pragma unroll
    for (int i = 0; i < 2; ++i) {
      int row = row0 + i * 16 + r; if (row >= n) row = n - 1;
      const float* fp = A + (size_t)row * 64 + kofs;
      float4 u = *(const float4*)fp;
      float4 v = *(const float4*)(fp + 4);
      a[i] = (bf16x8){(bf16_t)u.x, (bf16_t)u.y, (bf16_t)u.z, (bf16_t)u.w,
                      (bf16_t)v.x, (bf16_t)v.y, (bf16_t)v.z, (bf16_t)v.w};
    }
    #pragma unroll
    for (int c = 0; c < 8; ++c) {
      bf16x8 b = W1V[(kt * 8 + c) * 64 + lane];
      acc[0][c] = __builtin_amdgcn_mfma_f32_16x16x32_bf16(a[0], b, acc[0][c], 0, 0, 0);
      acc[1][c] = __builtin_amdgcn_mfma_f32_16x16x32_bf16(a[1], b, acc[1][c], 0, 0, 0);
    }
  }

  // epilogue 1: +b1, ELU, store bf16 to swizzled LDS
  #pragma unroll
  for (int c = 0; c < 8; ++c) {
    const int col = c * 16 + r;
    const float bv = b1[col];
    #pragma unroll
    for (int i = 0; i < 2; ++i)
      #pragma unroll
      for (int q = 0; q < 4; ++q) {
        int rloc = wv * 32 + i * 16 + kb * 4 + q;
        float v = acc[i][c][q] + bv;
        v = v > 0.f ? v : expm1f(v);
        int off = (rloc * 256 + col * 2) ^ ((rloc & 7) << 4);
        *(bf16_t*)(h1s + off) = (bf16_t)v;
      }
  }
  __syncthreads();

  // ---- phase 2: K=128, A from LDS ----
  #pragma unroll
  for (int i = 0; i < 2; ++i)
    #pragma unroll
    for (int c = 0; c < 8; ++c) acc[i][c] = (f32x4){0.f, 0.f, 0.f, 0.f};

  #pragma unroll
  for (int kt = 0; kt < 4; ++kt) {
    const int kbyte = (kt * 32 + kb * 8) * 2;
    bf16x8 a[2];
    #pragma unroll
    for (int i = 0; i < 2; ++i) {
      int rloc = wv * 32 + i * 16 + r;
      int off = (rloc * 256 + kbyte) ^ ((rloc & 7) << 4);
      a[i] = *(const bf16x8*)(h1s + off);
    }
    #pragma unroll
    for (int c = 0; c < 8; ++c) {
      bf16x8 b = W2V[(kt * 8 + c) * 64 + lane];
      acc[0][c] = __builtin_amdgcn_mfma_f32_16x16x32_bf16(a[0], b, acc[0][c], 0, 0, 0);
      acc[1][c] = __builtin_amdgcn_mfma_f32_16x16x32_bf16(a[1], b, acc[1][c], 0, 0, 0);
    }
  }

  #pragma unroll
  for (int c = 0; c < 8; ++c) {
    const int col = c * 16 + r;
    const float bv = b2[col];
    #pragma unroll
    for (int i = 0; i < 2; ++i)
      #pragma unroll
      for (int q = 0; q < 4; ++q) {
        int row = row0 + i * 16 + kb * 4 + q;
        if (row < n) {
          float v = acc[i][c][q] + bv;
          v = v > 0.f ? v : expm1f(v);
          outb[(size_t)row * 128 + col] = (bf16_t)v;
        }
      }
  }
}

// ---------------- MFMA dense (concat A1 bf16 + A2 bf16-or-f32) ----------------
template<int K1, int K2, bool DOELU, bool OUTF32, bool A2F32>
__global__ __launch_bounds__(256) void mf_dense(
    const bf16_t* __restrict__ A1, const bf16_t* __restrict__ A2b,
    const float* __restrict__ A2f,
    const bf16_t* __restrict__ Wf, const float* __restrict__ bias,
    bf16_t* __restrict__ outb, float* __restrict__ outf, int n)
{
  constexpr int K   = K1 + K2;
  constexpr int NKT = K / 32;
  static_assert(K1 % 32 == 0, "K-step must not straddle A1/A2");

  const int tid  = threadIdx.x;
  const int wv   = tid >> 6;
  const int lane = tid & 63;
  const int r    = lane & 15;
  const int kb   = lane >> 4;
  const int row0 = blockIdx.x * 128 + wv * 32;

  f32x4 acc[2][8];
  #pragma unroll
  for (int i = 0; i < 2; ++i)
    #pragma unroll
    for (int c = 0; c < 8; ++c) acc[i][c] = (f32x4){0.f, 0.f, 0.f, 0.f};

  const bf16x8* WfV = (const bf16x8*)Wf;

  #pragma unroll
  for (int kt = 0; kt < NKT; ++kt) {
    const int kofs = kt * 32 + kb * 8;
    bf16x8 a[2];
    #pragma unroll
    for (int i = 0; i < 2; ++i) {
      int row = row0 + i * 16 + r; if (row >= n) row = n - 1;
      if (K2 == 0 || kofs < K1) {
        a[i] = *(const bf16x8*)(A1 + (size_t)row * K1 + kofs);
      } else if (A2F32) {
        const float* fp = A2f + (size_t)row * K2 + (kofs - K1);
        float4 u = *(const float4*)fp;
        float4 v = *(const float4*)(fp + 4);
        a[i] = (bf16x8){(bf16_t)u.x, (bf16_t)u.y, (bf16_t)u.z, (bf16_t)u.w,
                        (bf16_t)v.x, (bf16_t)v.y, (bf16_t)v.z, (bf16_t)v.w};
      } else {
        a[i] = *(const bf16x8*)(A2b + (size_t)row * K2 + (kofs - K1));
      }
    }
    #pragma unroll
    for (int c = 0; c < 8; ++c) {
      bf16x8 b = WfV[(kt * 8 + c) * 64 + lane];
      acc[0][c] = __builtin_amdgcn_mfma_f32_16x16x32_bf16(a[0], b, acc[0][c], 0, 0, 0);
      acc[1][c] = __builtin_amdgcn_mfma_f32_16x16x32_bf16(a[1], b, acc[1][c], 0, 0, 0);
    }
  }

  #pragma unroll
  for (int c = 0; c < 8; ++c) {
    const int col = c * 16 + r;
    const float bv = bias ? bias[col] : 0.f;
    #pragma unroll
    for (int i = 0; i < 2; ++i)
      #pragma unroll
      for (int q = 0; q < 4; ++q) {
        int row = row0 + i * 16 + kb * 4 + q;
        if (row < n) {
          float v = acc[i][c][q] + bv;
          if (DOELU) v = v > 0.f ? v : expm1f(v);
          if (OUTF32) outf[(size_t)row * 128 + col] = v;
          else        outb[(size_t)row * 128 + col] = (bf16_t)v;
        }
      }
  }
}

// ---------------- GCN aggregate (round-6 numerics, half-wave layout) ----------------
// agg[d] = dinv[d] * ( sum_{s} xg[s]*dinv[s] + xg[d]*dinv[d] ) + bgc
__global__ __launch_bounds__(256) void gcn_agg3(
    const int* __restrict__ row_off, const int* __restrict__ csr,
    const float* __restrict__ dinv, const bf16_t* __restrict__ xg,
    const float* __restrict__ bgc, bf16_t* __restrict__ agg, int n)
{
  int w = (int)((blockIdx.x * (unsigned)blockDim.x + threadIdx.x) >> 6);
  if (w >= n) return;
  const int lane = threadIdx.x & 63;
  const int h  = lane >> 5;     // edge parity handled by this half-wave
  const int li = lane & 31;     // feature group: cols 4*li .. 4*li+3

  const float dd = dinv[w];
  f32x4 acc = (f32x4){0.f, 0.f, 0.f, 0.f};
  if (h == 0) {
    bf16x4 sv = ((const bf16x4*)(xg + (size_t)w * 128))[li];
    acc[0] = (float)sv[0] * dd; acc[1] = (float)sv[1] * dd;
    acc[2] = (float)sv[2] * dd; acc[3] = (float)sv[3] * dd;
  }

  const int e0 = row_off[w], e1 = row_off[w + 1];
  int e = e0;
  for (; e + 8 <= e1; e += 8) {
    #pragma unroll
    for (int u = 0; u < 4; ++u) {
      int s = csr[e + 2 * u + h];
      float ds = dinv[s];
      bf16x4 v = ((const bf16x4*)(xg + (size_t)s * 128))[li];
      acc[0] += (float)v[0] * ds; acc[1] += (float)v[1] * ds;
      acc[2] += (float)v[2] * ds; acc[3] += (float)v[3] * ds;
    }
  }
  for (; e < e1; e += 2) {
    int idx = e + h;
    int cidx = idx < e1 ? idx : e1 - 1;
    int s = csr[cidx];
    float ds = idx < e1 ? dinv[s] : 0.f;
    bf16x4 v = ((const bf16x4*)(xg + (size_t)s * 128))[li];
    acc[0] += (float)v[0] * ds; acc[1] += (float)v[1] * ds;
    acc[2] += (float)v[2] * ds; acc[3] += (float)v[3] * ds;
  }

  #pragma unroll
  for (int j = 0; j < 4; ++j) acc[j] += __shfl_xor(acc[j], 32);

  if (h == 0) {
    f32x4 bb = ((const f32x4*)bgc)[li];
    bf16x4 o;
    o[0] = (bf16_t)(acc[0] * dd + bb[0]); o[1] = (bf16_t)(acc[1] * dd + bb[1]);
    o[2] = (bf16_t)(acc[2] * dd + bb[2]); o[3] = (bf16_t)(acc[3] * dd + bb[3]);
    ((bf16x4*)(agg + (size_t)w * 128))[li] = o;
  }
}

// ---------------- launch ----------------

extern "C" void kernel_launch(void* const* d_in, const int* in_sizes, int n_in,
                              void* d_out, int out_size, void* d_ws, size_t ws_size,
                              hipStream_t stream) {
  (void)in_sizes; (void)n_in; (void)out_size; (void)ws_size;
  const float* feats = (const float*)d_in[0];
  const int*   edges = (const int*)d_in[1];
  const int*   batch = (const int*)d_in[2];
  const float* W1  = (const float*)d_in[3];
  const float* b1  = (const float*)d_in[4];
  const float* W2  = (const float*)d_in[5];
  const float* b2  = (const float*)d_in[6];
  const float* Wgc = (const float*)d_in[7];
  const float* bgc = (const float*)d_in[8];
  const float* Wc  = (const float*)d_in[9];
  const float* bc  = (const float*)d_in[10];
  float* out = (float*)d_out;

  // workspace layout (bf16 activations)
  bf16_t* h2b  = (bf16_t*)d_ws;                      // [NN*128] (nfeats)
  bf16_t* xgb  = h2b  + (size_t)NN * 128;            // [NN*128] (GCN linear out)
  bf16_t* aggb = xgb  + (size_t)NN * 128;            // [NN*128]
  float*  dinv = (float*)(aggb + (size_t)NN * 128);  // [NN]
  bf16_t* wall = (bf16_t*)(dinv + NN);               // [81920] all four frag-ordered Ws
  bf16_t* w1f  = wall;
  bf16_t* w2f  = wall + 8192;
  bf16_t* wgcf = wall + 24576;
  bf16_t* wcf  = wall + 49152;

  // scratch in the FRONT of d_out (dead before final mf_dense writes it)
  int* scr     = (int*)d_out;
  int* csr_src = scr;                   // [NE]
  int* row_off = csr_src + NE;          // [NN+1]
  int* H       = row_off + NN + 1;      // [NH]
  int* Hincl   = H + NH;                // [NH]
  int* Hoff    = Hincl + NH;            // [NH+1]
  int* boff    = Hoff + NH + 1;         // [NB1+1]
  int* bsum2   = boff + NB1 + 1;        // [512]
  unsigned long long* ebuf =
      (unsigned long long*)(((uintptr_t)(bsum2 + 512) + 7) & ~(uintptr_t)7);  // [NE]

  const int* esrc = edges;
  const int* edst = edges + NE;

  const int nscH = (NH + SB - 1) / SB;   // 151

  // --- CSR build: block-owned bucket sort + fused finalize ---
  histA   <<<NBLK, 256, 0, stream>>>(edst, H, NE);
  scan_blk<<<nscH, SB, 0, stream>>>(H, Hincl, bsum2, NH);
  scan_top<<<1, 512, 0, stream>>>(bsum2, nscH);
  scan_add<<<nscH, SB, 0, stream>>>(Hincl, H, bsum2, Hoff, NH);
  boff_k  <<<1, 256, 0, stream>>>(Hoff, boff);
  scatterA<<<NBLK, 256, 0, stream>>>(esrc, edst, Hoff, ebuf, NE);
  bfin    <<<NB1, 512, 0, stream>>>(ebuf, boff, row_off, dinv, csr_src, NN);

  // --- weight prep (single launch) ---
  wprep4<<<320, 256, 0, stream>>>(W1, W2, Wgc, Wc, wall);

  // --- dense chain on MFMA ---
  const int nb = (NN + 127) / 128;
  mf_dense12<<<nb, 256, 0, stream>>>(feats, w1f, b1, w2f, b2, h2b, NN);
  mf_dense<128, 64, false, false, true><<<nb, 256, 0, stream>>>(
      h2b, nullptr, feats, wgcf, nullptr, xgb, nullptr, NN);

  // --- GCN aggregate ---
  long long wthreads = (long long)NN * 64;
  gcn_agg3<<<(int)((wthreads + 255) / 256), 256, 0, stream>>>(
      row_off, csr_src, dinv, xgb, bgc, aggb, NN);

  // --- output layer (fp32 into d_out, overwrites scratch) ---
  mf_dense<128, 128, true, true, false><<<nb, 256, 0, stream>>>(
      h2b, aggb, nullptr, wcf, bc, nullptr, out, NN);

  // tail outputs: edges and batch, as float
  size_t off = (size_t)NN * 128;
  i2f_k<<<(2 * NE + 255) / 256, 256, 0, stream>>>(edges, out + off, 2 * NE);
  i2f_k<<<(NN + 255) / 256, 256, 0, stream>>>(batch, out + off + (size_t)2 * NE, NN);
}

// Round 10
// 274.462 us; speedup vs baseline: 2.8118x; 1.0343x over previous
//
#include <hip/hip_runtime.h>
#include <hip/hip_bf16.h>
#include <hip/hip_fp8.h>

constexpr int NN = 100000;
constexpr int NE = 1600000;

constexpr int SH1  = 9;                      // 512 nodes per bucket
constexpr int NB1  = (NN + 511) >> SH1;      // 196 buckets
constexpr int EB   = 8192;                   // edges per pass-A block
constexpr int NBLK = (NE + EB - 1) / EB;     // 196 blocks
constexpr int NH   = NB1 * NBLK;             // 38416 histogram cells

constexpr float FP8_SCL  = 128.f;
constexpr float FP8_ISCL = 1.f / 128.f;

typedef __bf16 bf16_t;
typedef bf16_t bf16x8 __attribute__((ext_vector_type(8)));
typedef bf16_t bf16x4 __attribute__((ext_vector_type(4)));
typedef float  f32x4  __attribute__((ext_vector_type(4)));

// fp8 helpers: encode via HIP type (epilogue, cheap); decode via HW cvt builtin.
// NOTE: __builtin_amdgcn_cvt_f32_fp8 requires sel to be a LITERAL constant ->
// template parameter so each instantiation carries a compile-time constant.
__device__ inline unsigned char f_to_fp8(float v) {
  __hip_fp8_e4m3 q(v);
  return q.__x;
}
template<int SEL>
__device__ inline float fp8_to_f(unsigned int word) {
#if __has_builtin(__builtin_amdgcn_cvt_f32_fp8)
  return __builtin_amdgcn_cvt_f32_fp8(word, SEL);
#else
  __hip_fp8_e4m3 t; t.__x = (word >> (8 * SEL)) & 0xff; return (float)t;
#endif
}

// decode 4 packed fp8 and FMA into acc with scale
__device__ inline void fp8x4_fma(f32x4& acc, unsigned int v, float s) {
  acc[0] += fp8_to_f<0>(v) * s;
  acc[1] += fp8_to_f<1>(v) * s;
  acc[2] += fp8_to_f<2>(v) * s;
  acc[3] += fp8_to_f<3>(v) * s;
}

// ---------------- generic scan chain (used for H only) ----------------
constexpr int SB = 256;

__global__ void scan_blk(const int* __restrict__ in, int* __restrict__ incl,
                         int* __restrict__ bsum, int n) {
  __shared__ int sm[SB];
  int i = blockIdx.x * SB + threadIdx.x;
  int v = (i < n) ? in[i] : 0;
  sm[threadIdx.x] = v;
  __syncthreads();
  for (int off = 1; off < SB; off <<= 1) {
    int t = (threadIdx.x >= off) ? sm[threadIdx.x - off] : 0;
    __syncthreads();
    sm[threadIdx.x] += t;
    __syncthreads();
  }
  if (i < n) incl[i] = sm[threadIdx.x];
  if (threadIdx.x == SB - 1) bsum[blockIdx.x] = sm[SB - 1];
}

__global__ void scan_top(int* __restrict__ bsum, int nb) {
  __shared__ int sm[512];
  int t = threadIdx.x;
  int v = (t < nb) ? bsum[t] : 0;
  sm[t] = v;
  __syncthreads();
  for (int off = 1; off < 512; off <<= 1) {
    int u = (t >= off) ? sm[t - off] : 0;
    __syncthreads();
    sm[t] += u;
    __syncthreads();
  }
  if (t < nb) bsum[t] = sm[t] - v;   // exclusive
}

__global__ void scan_add(const int* __restrict__ incl, const int* __restrict__ in,
                         const int* __restrict__ bsum, int* __restrict__ outoff, int n) {
  int i = blockIdx.x * SB + threadIdx.x;
  if (i < n) {
    int off = bsum[blockIdx.x];
    outoff[i] = off + incl[i] - in[i];    // exclusive prefix
    if (i == n - 1) outoff[n] = off + incl[i];
  }
}

// ---------------- pass A: block-local histogram + owned-range scatter ----------------

__global__ __launch_bounds__(256) void histA(const int* __restrict__ dst,
                                             int* __restrict__ H, int e) {
  __shared__ int h[NB1];
  for (int i = threadIdx.x; i < NB1; i += 256) h[i] = 0;
  __syncthreads();
  int base = blockIdx.x * EB;
  int end = min(base + EB, e);
  for (int i = base + threadIdx.x; i < end; i += 256)
    atomicAdd(&h[dst[i] >> SH1], 1);
  __syncthreads();
  for (int i = threadIdx.x; i < NB1; i += 256)
    H[i * NBLK + blockIdx.x] = h[i];
}

__global__ void boff_k(const int* __restrict__ Hoff, int* __restrict__ boff) {
  int i = blockIdx.x * blockDim.x + threadIdx.x;
  if (i < NB1) boff[i] = Hoff[i * NBLK];
  if (i == NB1) boff[NB1] = NE;
}

// each block writes its edges into its exclusive (bucket,block) ranges; LDS cursors only
__global__ __launch_bounds__(256) void scatterA(
    const int* __restrict__ src, const int* __restrict__ dst,
    const int* __restrict__ Hoff, unsigned long long* __restrict__ ebuf, int e) {
  __shared__ int cur[NB1];
  for (int i = threadIdx.x; i < NB1; i += 256)
    cur[i] = Hoff[i * NBLK + blockIdx.x];
  __syncthreads();
  int base = blockIdx.x * EB;
  int end = min(base + EB, e);
  for (int i = base + threadIdx.x; i < end; i += 256) {
    int d = dst[i], s = src[i];
    int pos = atomicAdd(&cur[d >> SH1], 1);
    ebuf[pos] = ((unsigned long long)(unsigned)d << 32) | (unsigned)s;
  }
}

// ---------------- pass B fused: per-bucket degree + scan + row_off + dinv + placement ----------------

__global__ __launch_bounds__(512) void bfin(const unsigned long long* __restrict__ ebuf,
                                            const int* __restrict__ boff,
                                            int* __restrict__ row_off, float* __restrict__ dinv,
                                            int* __restrict__ csr, int n) {
  __shared__ int cnt[512];
  __shared__ int loc[512];
  const int tid = threadIdx.x;
  const int b = blockIdx.x;
  cnt[tid] = 0;
  __syncthreads();
  const int e0 = boff[b], e1 = boff[b + 1];
  for (int e = e0 + tid; e < e1; e += 512)
    atomicAdd(&cnt[(int)(ebuf[e] >> 32) & 511], 1);
  __syncthreads();
  // inclusive scan over 512
  loc[tid] = cnt[tid];
  __syncthreads();
  for (int off = 1; off < 512; off <<= 1) {
    int t = (tid >= off) ? loc[tid - off] : 0;
    __syncthreads();
    loc[tid] += t;
    __syncthreads();
  }
  const int excl = loc[tid] - cnt[tid];
  const int node = (b << SH1) + tid;
  if (node < n) {
    row_off[node] = boff[b] + excl;
    dinv[node] = rsqrtf((float)cnt[tid] + 1.0f);   // +1 self-loop
  }
  if (b == NB1 - 1 && tid == 0) row_off[n] = NE;
  // reuse cnt[] as cursors
  cnt[tid] = boff[b] + excl;
  __syncthreads();
  for (int e = e0 + tid; e < e1; e += 512) {
    unsigned long long v = ebuf[e];
    int dl = (int)(v >> 32) & 511;
    int s  = (int)(v & 0xffffffffu);
    int slot = atomicAdd(&cnt[dl], 1);
    csr[slot] = s;
  }
}

// ---------------- misc ----------------

__global__ void i2f_k(const int* __restrict__ in, float* __restrict__ out, int n) {
  int i = blockIdx.x * blockDim.x + threadIdx.x;
  if (i < n) out[i] = (float)in[i];
}

// all four weight shuffles in one launch. Wf regions: W1[0,8192) W2[8192,24576)
// Wgc[24576,49152) Wc[49152,81920). grid = 320*256 = 81920 exactly.
__global__ void wprep4(const float* __restrict__ W1, const float* __restrict__ W2,
                       const float* __restrict__ Wgc, const float* __restrict__ Wc,
                       bf16_t* __restrict__ Wf) {
  int idx = blockIdx.x * blockDim.x + threadIdx.x;
  const float* W; int base;
  if      (idx < 8192)  { W = W1;  base = 0; }
  else if (idx < 24576) { W = W2;  base = 8192; }
  else if (idx < 49152) { W = Wgc; base = 24576; }
  else                  { W = Wc;  base = 49152; }
  int il   = idx - base;
  int j    = il & 7;
  int lane = (il >> 3) & 63;
  int c    = (il >> 9) & 7;
  int kt   = il >> 12;
  int k    = kt * 32 + (lane >> 4) * 8 + j;
  int col  = c * 16 + (lane & 15);
  Wf[idx] = (bf16_t)W[(size_t)k * 128 + col];
}

// ---------------- fused dense layers 1+2 ----------------
// h2 = elu( elu(feats @ W1 + b1) @ W2 + b2 ); feats read as f32; h1 staged in
// XOR-swizzled LDS (2-way bank alias = free). Each wave owns its 32 rows end-to-end.
__global__ __launch_bounds__(256) void mf_dense12(
    const float* __restrict__ A, const bf16_t* __restrict__ W1f, const float* __restrict__ b1,
    const bf16_t* __restrict__ W2f, const float* __restrict__ b2,
    bf16_t* __restrict__ outb, int n)
{
  __shared__ __align__(16) char h1s[128 * 256];   // 128 rows x 128 bf16 (256 B/row)
  const int tid  = threadIdx.x;
  const int wv   = tid >> 6;
  const int lane = tid & 63;
  const int r    = lane & 15;
  const int kb   = lane >> 4;
  const int row0 = blockIdx.x * 128 + wv * 32;

  const bf16x8* W1V = (const bf16x8*)W1f;
  const bf16x8* W2V = (const bf16x8*)W2f;

  // ---- phase 1: K=64, A = f32 feats ----
  f32x4 acc[2][8];
  #pragma unroll
  for (int i = 0; i < 2; ++i)
    #pragma unroll
    for (int c = 0; c < 8; ++c) acc[i][c] = (f32x4){0.f, 0.f, 0.f, 0.f};

  #pragma unroll
  for (int kt = 0; kt < 2; ++kt) {
    const int kofs = kt * 32 + kb * 8;
    bf16x8 a[2];
    #pragma unroll
    for (int i = 0; i < 2; ++i) {
      int row = row0 + i * 16 + r; if (row >= n) row = n - 1;
      const float* fp = A + (size_t)row * 64 + kofs;
      float4 u = *(const float4*)fp;
      float4 v = *(const float4*)(fp + 4);
      a[i] = (bf16x8){(bf16_t)u.x, (bf16_t)u.y, (bf16_t)u.z, (bf16_t)u.w,
                      (bf16_t)v.x, (bf16_t)v.y, (bf16_t)v.z, (bf16_t)v.w};
    }
    #pragma unroll
    for (int c = 0; c < 8; ++c) {
      bf16x8 b = W1V[(kt * 8 + c) * 64 + lane];
      acc[0][c] = __builtin_amdgcn_mfma_f32_16x16x32_bf16(a[0], b, acc[0][c], 0, 0, 0);
      acc[1][c] = __builtin_amdgcn_mfma_f32_16x16x32_bf16(a[1], b, acc[1][c], 0, 0, 0);
    }
  }

  // epilogue 1: +b1, ELU, store bf16 to swizzled LDS
  #pragma unroll
  for (int c = 0; c < 8; ++c) {
    const int col = c * 16 + r;
    const float bv = b1[col];
    #pragma unroll
    for (int i = 0; i < 2; ++i)
      #pragma unroll
      for (int q = 0; q < 4; ++q) {
        int rloc = wv * 32 + i * 16 + kb * 4 + q;
        float v = acc[i][c][q] + bv;
        v = v > 0.f ? v : expm1f(v);
        int off = (rloc * 256 + col * 2) ^ ((rloc & 7) << 4);
        *(bf16_t*)(h1s + off) = (bf16_t)v;
      }
  }
  __syncthreads();

  // ---- phase 2: K=128, A from LDS ----
  #pragma unroll
  for (int i = 0; i < 2; ++i)
    #pragma unroll
    for (int c = 0; c < 8; ++c) acc[i][c] = (f32x4){0.f, 0.f, 0.f, 0.f};

  #pragma unroll
  for (int kt = 0; kt < 4; ++kt) {
    const int kbyte = (kt * 32 + kb * 8) * 2;
    bf16x8 a[2];
    #pragma unroll
    for (int i = 0; i < 2; ++i) {
      int rloc = wv * 32 + i * 16 + r;
      int off = (rloc * 256 + kbyte) ^ ((rloc & 7) << 4);
      a[i] = *(const bf16x8*)(h1s + off);
    }
    #pragma unroll
    for (int c = 0; c < 8; ++c) {
      bf16x8 b = W2V[(kt * 8 + c) * 64 + lane];
      acc[0][c] = __builtin_amdgcn_mfma_f32_16x16x32_bf16(a[0], b, acc[0][c], 0, 0, 0);
      acc[1][c] = __builtin_amdgcn_mfma_f32_16x16x32_bf16(a[1], b, acc[1][c], 0, 0, 0);
    }
  }

  #pragma unroll
  for (int c = 0; c < 8; ++c) {
    const int col = c * 16 + r;
    const float bv = b2[col];
    #pragma unroll
    for (int i = 0; i < 2; ++i)
      #pragma unroll
      for (int q = 0; q < 4; ++q) {
        int row = row0 + i * 16 + kb * 4 + q;
        if (row < n) {
          float v = acc[i][c][q] + bv;
          v = v > 0.f ? v : expm1f(v);
          outb[(size_t)row * 128 + col] = (bf16_t)v;
        }
      }
  }
}

// ---------------- MFMA dense (concat A1 bf16 + A2 bf16-or-f32) ----------------
// OMODE: 0 = bf16 out, 1 = f32 out, 2 = fp8 out (value * FP8_SCL)
template<int K1, int K2, bool DOELU, int OMODE, bool A2F32>
__global__ __launch_bounds__(256) void mf_dense(
    const bf16_t* __restrict__ A1, const bf16_t* __restrict__ A2b,
    const float* __restrict__ A2f,
    const bf16_t* __restrict__ Wf, const float* __restrict__ bias,
    bf16_t* __restrict__ outb, float* __restrict__ outf,
    unsigned char* __restrict__ outq, int n)
{
  constexpr int K   = K1 + K2;
  constexpr int NKT = K / 32;
  static_assert(K1 % 32 == 0, "K-step must not straddle A1/A2");

  const int tid  = threadIdx.x;
  const int wv   = tid >> 6;
  const int lane = tid & 63;
  const int r    = lane & 15;
  const int kb   = lane >> 4;
  const int row0 = blockIdx.x * 128 + wv * 32;

  f32x4 acc[2][8];
  #pragma unroll
  for (int i = 0; i < 2; ++i)
    #pragma unroll
    for (int c = 0; c < 8; ++c) acc[i][c] = (f32x4){0.f, 0.f, 0.f, 0.f};

  const bf16x8* WfV = (const bf16x8*)Wf;

  #pragma unroll
  for (int kt = 0; kt < NKT; ++kt) {
    const int kofs = kt * 32 + kb * 8;
    bf16x8 a[2];
    #pragma unroll
    for (int i = 0; i < 2; ++i) {
      int row = row0 + i * 16 + r; if (row >= n) row = n - 1;
      if (K2 == 0 || kofs < K1) {
        a[i] = *(const bf16x8*)(A1 + (size_t)row * K1 + kofs);
      } else if (A2F32) {
        const float* fp = A2f + (size_t)row * K2 + (kofs - K1);
        float4 u = *(const float4*)fp;
        float4 v = *(const float4*)(fp + 4);
        a[i] = (bf16x8){(bf16_t)u.x, (bf16_t)u.y, (bf16_t)u.z, (bf16_t)u.w,
                        (bf16_t)v.x, (bf16_t)v.y, (bf16_t)v.z, (bf16_t)v.w};
      } else {
        a[i] = *(const bf16x8*)(A2b + (size_t)row * K2 + (kofs - K1));
      }
    }
    #pragma unroll
    for (int c = 0; c < 8; ++c) {
      bf16x8 b = WfV[(kt * 8 + c) * 64 + lane];
      acc[0][c] = __builtin_amdgcn_mfma_f32_16x16x32_bf16(a[0], b, acc[0][c], 0, 0, 0);
      acc[1][c] = __builtin_amdgcn_mfma_f32_16x16x32_bf16(a[1], b, acc[1][c], 0, 0, 0);
    }
  }

  #pragma unroll
  for (int c = 0; c < 8; ++c) {
    const int col = c * 16 + r;
    const float bv = bias ? bias[col] : 0.f;
    #pragma unroll
    for (int i = 0; i < 2; ++i)
      #pragma unroll
      for (int q = 0; q < 4; ++q) {
        int row = row0 + i * 16 + kb * 4 + q;
        if (row < n) {
          float v = acc[i][c][q] + bv;
          if (DOELU) v = v > 0.f ? v : expm1f(v);
          if (OMODE == 0)      outb[(size_t)row * 128 + col] = (bf16_t)v;
          else if (OMODE == 1) outf[(size_t)row * 128 + col] = v;
          else                 outq[(size_t)row * 128 + col] = f_to_fp8(v * FP8_SCL);
        }
      }
  }
}

// ---------------- GCN aggregate v4: fp8 table, 128 B/row (one line) ----------------
// agg[d] = dinv[d] * ( sum_{s} xq[s]*dinv[s] + xq[d]*dinv[d] ) / FP8_SCL + bgc
__global__ __launch_bounds__(256) void gcn_agg4(
    const int* __restrict__ row_off, const int* __restrict__ csr,
    const float* __restrict__ dinv, const unsigned char* __restrict__ xq,
    const float* __restrict__ bgc, bf16_t* __restrict__ agg, int n)
{
  int w = (int)((blockIdx.x * (unsigned)blockDim.x + threadIdx.x) >> 6);
  if (w >= n) return;
  const int lane = threadIdx.x & 63;
  const int h  = lane >> 5;     // edge parity handled by this half-wave
  const int li = lane & 31;     // feature group: cols 4*li .. 4*li+3

  const float dd = dinv[w];
  f32x4 acc = (f32x4){0.f, 0.f, 0.f, 0.f};
  if (h == 0) {
    unsigned int sv = ((const unsigned int*)(xq + (size_t)w * 128))[li];
    fp8x4_fma(acc, sv, dd);
  }

  const int e0 = row_off[w], e1 = row_off[w + 1];
  int e = e0;
  for (; e + 8 <= e1; e += 8) {
    #pragma unroll
    for (int u = 0; u < 4; ++u) {
      int s = csr[e + 2 * u + h];
      float ds = dinv[s];
      unsigned int v = ((const unsigned int*)(xq + (size_t)s * 128))[li];
      fp8x4_fma(acc, v, ds);
    }
  }
  for (; e < e1; e += 2) {
    int idx = e + h;
    int cidx = idx < e1 ? idx : e1 - 1;
    int s = csr[cidx];
    float ds = idx < e1 ? dinv[s] : 0.f;
    unsigned int v = ((const unsigned int*)(xq + (size_t)s * 128))[li];
    fp8x4_fma(acc, v, ds);
  }

  #pragma unroll
  for (int j = 0; j < 4; ++j) acc[j] += __shfl_xor(acc[j], 32);

  if (h == 0) {
    const float sc = dd * FP8_ISCL;
    f32x4 bb = ((const f32x4*)bgc)[li];
    bf16x4 o;
    o[0] = (bf16_t)(acc[0] * sc + bb[0]); o[1] = (bf16_t)(acc[1] * sc + bb[1]);
    o[2] = (bf16_t)(acc[2] * sc + bb[2]); o[3] = (bf16_t)(acc[3] * sc + bb[3]);
    ((bf16x4*)(agg + (size_t)w * 128))[li] = o;
  }
}

// ---------------- launch ----------------

extern "C" void kernel_launch(void* const* d_in, const int* in_sizes, int n_in,
                              void* d_out, int out_size, void* d_ws, size_t ws_size,
                              hipStream_t stream) {
  (void)in_sizes; (void)n_in; (void)out_size; (void)ws_size;
  const float* feats = (const float*)d_in[0];
  const int*   edges = (const int*)d_in[1];
  const int*   batch = (const int*)d_in[2];
  const float* W1  = (const float*)d_in[3];
  const float* b1  = (const float*)d_in[4];
  const float* W2  = (const float*)d_in[5];
  const float* b2  = (const float*)d_in[6];
  const float* Wgc = (const float*)d_in[7];
  const float* bgc = (const float*)d_in[8];
  const float* Wc  = (const float*)d_in[9];
  const float* bc  = (const float*)d_in[10];
  float* out = (float*)d_out;

  // workspace layout
  bf16_t* h2b  = (bf16_t*)d_ws;                      // [NN*128] bf16 (nfeats)
  bf16_t* aggb = h2b  + (size_t)NN * 128;            // [NN*128] bf16
  unsigned char* xq8 = (unsigned char*)(aggb + (size_t)NN * 128);  // [NN*128] fp8
  float*  dinv = (float*)(xq8 + (size_t)NN * 128);   // [NN]
  bf16_t* wall = (bf16_t*)(dinv + NN);               // [81920] all four frag-ordered Ws
  bf16_t* w1f  = wall;
  bf16_t* w2f  = wall + 8192;
  bf16_t* wgcf = wall + 24576;
  bf16_t* wcf  = wall + 49152;

  // scratch in the FRONT of d_out (dead before final mf_dense writes it)
  int* scr     = (int*)d_out;
  int* csr_src = scr;                   // [NE]
  int* row_off = csr_src + NE;          // [NN+1]
  int* H       = row_off + NN + 1;      // [NH]
  int* Hincl   = H + NH;                // [NH]
  int* Hoff    = Hincl + NH;            // [NH+1]
  int* boff    = Hoff + NH + 1;         // [NB1+1]
  int* bsum2   = boff + NB1 + 1;        // [512]
  unsigned long long* ebuf =
      (unsigned long long*)(((uintptr_t)(bsum2 + 512) + 7) & ~(uintptr_t)7);  // [NE]

  const int* esrc = edges;
  const int* edst = edges + NE;

  const int nscH = (NH + SB - 1) / SB;   // 151

  // --- CSR build: block-owned bucket sort + fused finalize ---
  histA   <<<NBLK, 256, 0, stream>>>(edst, H, NE);
  scan_blk<<<nscH, SB, 0, stream>>>(H, Hincl, bsum2, NH);
  scan_top<<<1, 512, 0, stream>>>(bsum2, nscH);
  scan_add<<<nscH, SB, 0, stream>>>(Hincl, H, bsum2, Hoff, NH);
  boff_k  <<<1, 256, 0, stream>>>(Hoff, boff);
  scatterA<<<NBLK, 256, 0, stream>>>(esrc, edst, Hoff, ebuf, NE);
  bfin    <<<NB1, 512, 0, stream>>>(ebuf, boff, row_off, dinv, csr_src, NN);

  // --- weight prep (single launch) ---
  wprep4<<<320, 256, 0, stream>>>(W1, W2, Wgc, Wc, wall);

  // --- dense chain on MFMA ---
  const int nb = (NN + 127) / 128;
  mf_dense12<<<nb, 256, 0, stream>>>(feats, w1f, b1, w2f, b2, h2b, NN);
  // GCN linear layer -> fp8 table (scaled x128)
  mf_dense<128, 64, false, 2, true><<<nb, 256, 0, stream>>>(
      h2b, nullptr, feats, wgcf, nullptr, nullptr, nullptr, xq8, NN);

  // --- GCN aggregate (fp8 gather) ---
  long long wthreads = (long long)NN * 64;
  gcn_agg4<<<(int)((wthreads + 255) / 256), 256, 0, stream>>>(
      row_off, csr_src, dinv, xq8, bgc, aggb, NN);

  // --- output layer (fp32 into d_out, overwrites scratch) ---
  mf_dense<128, 128, true, 1, false><<<nb, 256, 0, stream>>>(
      h2b, aggb, nullptr, wcf, bc, nullptr, out, nullptr, NN);

  // tail outputs: edges and batch, as float
  size_t off = (size_t)NN * 128;
  i2f_k<<<(2 * NE + 255) / 256, 256, 0, stream>>>(edges, out + off, 2 * NE);
  i2f_k<<<(NN + 255) / 256, 256, 0, stream>>>(batch, out + off + (size_t)2 * NE, NN);
}

// Round 11
// 215.369 us; speedup vs baseline: 3.5833x; 1.2744x over previous
//
#include <hip/hip_runtime.h>
#include <hip/hip_bf16.h>
#include <hip/hip_fp8.h>

constexpr int NN = 100000;
constexpr int NE = 1600000;

constexpr int SH1  = 9;                      // 512 nodes per bucket
constexpr int NB1  = (NN + 511) >> SH1;      // 196 buckets
constexpr int EB   = 8192;                   // edges per pass-A block
constexpr int NBLK = (NE + EB - 1) / EB;     // 196 blocks
constexpr int NH   = NB1 * NBLK;             // 38416 histogram cells

constexpr float FP8_SCL  = 128.f;
constexpr float FP8_ISCL = 1.f / 128.f;

typedef __bf16 bf16_t;
typedef bf16_t bf16x8 __attribute__((ext_vector_type(8)));
typedef bf16_t bf16x4 __attribute__((ext_vector_type(4)));
typedef float  f32x4  __attribute__((ext_vector_type(4)));

// fast ELU: exp via v_exp_f32 (HW transcendental), ~1e-5 rel err vs expm1f
__device__ inline float elu_fast(float v) {
  return v > 0.f ? v : (__expf(v) - 1.f);
}

// fp8 helpers (sel must be a literal -> template parameter)
__device__ inline unsigned char f_to_fp8(float v) {
  __hip_fp8_e4m3 q(v);
  return q.__x;
}
template<int SEL>
__device__ inline float fp8_to_f(unsigned int word) {
#if __has_builtin(__builtin_amdgcn_cvt_f32_fp8)
  return __builtin_amdgcn_cvt_f32_fp8(word, SEL);
#else
  __hip_fp8_e4m3 t; t.__x = (word >> (8 * SEL)) & 0xff; return (float)t;
#endif
}
__device__ inline void fp8x4_fma(f32x4& acc, unsigned int v, float s) {
  acc[0] += fp8_to_f<0>(v) * s;
  acc[1] += fp8_to_f<1>(v) * s;
  acc[2] += fp8_to_f<2>(v) * s;
  acc[3] += fp8_to_f<3>(v) * s;
}

// ---------------- generic scan chain (used for H only) ----------------
constexpr int SB = 256;

__global__ void scan_blk(const int* __restrict__ in, int* __restrict__ incl,
                         int* __restrict__ bsum, int n) {
  __shared__ int sm[SB];
  int i = blockIdx.x * SB + threadIdx.x;
  int v = (i < n) ? in[i] : 0;
  sm[threadIdx.x] = v;
  __syncthreads();
  for (int off = 1; off < SB; off <<= 1) {
    int t = (threadIdx.x >= off) ? sm[threadIdx.x - off] : 0;
    __syncthreads();
    sm[threadIdx.x] += t;
    __syncthreads();
  }
  if (i < n) incl[i] = sm[threadIdx.x];
  if (threadIdx.x == SB - 1) bsum[blockIdx.x] = sm[SB - 1];
}

__global__ void scan_top(int* __restrict__ bsum, int nb) {
  __shared__ int sm[512];
  int t = threadIdx.x;
  int v = (t < nb) ? bsum[t] : 0;
  sm[t] = v;
  __syncthreads();
  for (int off = 1; off < 512; off <<= 1) {
    int u = (t >= off) ? sm[t - off] : 0;
    __syncthreads();
    sm[t] += u;
    __syncthreads();
  }
  if (t < nb) bsum[t] = sm[t] - v;   // exclusive
}

__global__ void scan_add(const int* __restrict__ incl, const int* __restrict__ in,
                         const int* __restrict__ bsum, int* __restrict__ outoff, int n) {
  int i = blockIdx.x * SB + threadIdx.x;
  if (i < n) {
    int off = bsum[blockIdx.x];
    outoff[i] = off + incl[i] - in[i];    // exclusive prefix
    if (i == n - 1) outoff[n] = off + incl[i];
  }
}

// ---------------- pass A: block-local histogram + owned-range scatter ----------------

__global__ __launch_bounds__(256) void histA(const int* __restrict__ dst,
                                             int* __restrict__ H, int e) {
  __shared__ int h[NB1];
  for (int i = threadIdx.x; i < NB1; i += 256) h[i] = 0;
  __syncthreads();
  int base = blockIdx.x * EB;
  int end = min(base + EB, e);
  for (int i = base + threadIdx.x; i < end; i += 256)
    atomicAdd(&h[dst[i] >> SH1], 1);
  __syncthreads();
  for (int i = threadIdx.x; i < NB1; i += 256)
    H[i * NBLK + blockIdx.x] = h[i];
}

__global__ void boff_k(const int* __restrict__ Hoff, int* __restrict__ boff) {
  int i = blockIdx.x * blockDim.x + threadIdx.x;
  if (i < NB1) boff[i] = Hoff[i * NBLK];
  if (i == NB1) boff[NB1] = NE;
}

__global__ __launch_bounds__(256) void scatterA(
    const int* __restrict__ src, const int* __restrict__ dst,
    const int* __restrict__ Hoff, unsigned long long* __restrict__ ebuf, int e) {
  __shared__ int cur[NB1];
  for (int i = threadIdx.x; i < NB1; i += 256)
    cur[i] = Hoff[i * NBLK + blockIdx.x];
  __syncthreads();
  int base = blockIdx.x * EB;
  int end = min(base + EB, e);
  for (int i = base + threadIdx.x; i < end; i += 256) {
    int d = dst[i], s = src[i];
    int pos = atomicAdd(&cur[d >> SH1], 1);
    ebuf[pos] = ((unsigned long long)(unsigned)d << 32) | (unsigned)s;
  }
}

// ---------------- pass B fused: degree + scan + row_off + dinv + placement ----------------

__global__ __launch_bounds__(512) void bfin(const unsigned long long* __restrict__ ebuf,
                                            const int* __restrict__ boff,
                                            int* __restrict__ row_off, float* __restrict__ dinv,
                                            int* __restrict__ csr, int n) {
  __shared__ int cnt[512];
  __shared__ int loc[512];
  const int tid = threadIdx.x;
  const int b = blockIdx.x;
  cnt[tid] = 0;
  __syncthreads();
  const int e0 = boff[b], e1 = boff[b + 1];
  for (int e = e0 + tid; e < e1; e += 512)
    atomicAdd(&cnt[(int)(ebuf[e] >> 32) & 511], 1);
  __syncthreads();
  loc[tid] = cnt[tid];
  __syncthreads();
  for (int off = 1; off < 512; off <<= 1) {
    int t = (tid >= off) ? loc[tid - off] : 0;
    __syncthreads();
    loc[tid] += t;
    __syncthreads();
  }
  const int excl = loc[tid] - cnt[tid];
  const int node = (b << SH1) + tid;
  if (node < n) {
    row_off[node] = boff[b] + excl;
    dinv[node] = rsqrtf((float)cnt[tid] + 1.0f);   // +1 self-loop
  }
  if (b == NB1 - 1 && tid == 0) row_off[n] = NE;
  cnt[tid] = boff[b] + excl;
  __syncthreads();
  for (int e = e0 + tid; e < e1; e += 512) {
    unsigned long long v = ebuf[e];
    int dl = (int)(v >> 32) & 511;
    int s  = (int)(v & 0xffffffffu);
    int slot = atomicAdd(&cnt[dl], 1);
    csr[slot] = s;
  }
}

// ---------------- misc ----------------

__global__ void i2f_k(const int* __restrict__ in, float* __restrict__ out, int n) {
  int i = blockIdx.x * blockDim.x + threadIdx.x;
  if (i < n) out[i] = (float)in[i];
}

// all four weight shuffles in one launch. grid = 320*256 = 81920 exactly.
__global__ void wprep4(const float* __restrict__ W1, const float* __restrict__ W2,
                       const float* __restrict__ Wgc, const float* __restrict__ Wc,
                       bf16_t* __restrict__ Wf) {
  int idx = blockIdx.x * blockDim.x + threadIdx.x;
  const float* W; int base;
  if      (idx < 8192)  { W = W1;  base = 0; }
  else if (idx < 24576) { W = W2;  base = 8192; }
  else if (idx < 49152) { W = Wgc; base = 24576; }
  else                  { W = Wc;  base = 49152; }
  int il   = idx - base;
  int j    = il & 7;
  int lane = (il >> 3) & 63;
  int c    = (il >> 9) & 7;
  int kt   = il >> 12;
  int k    = kt * 32 + (lane >> 4) * 8 + j;
  int col  = c * 16 + (lane & 15);
  Wf[idx] = (bf16_t)W[(size_t)k * 128 + col];
}

// ---------------- fused dense layers 1+2 (16 rows/wave, 64 rows/block) ----------------
// h2 = elu( elu(feats @ W1 + b1) @ W2 + b2 ); h1 staged per-wave in swizzled LDS.
__global__ __launch_bounds__(256) void mf_dense12(
    const float* __restrict__ A, const bf16_t* __restrict__ W1f, const float* __restrict__ b1,
    const bf16_t* __restrict__ W2f, const float* __restrict__ b2,
    bf16_t* __restrict__ outb, int n)
{
  __shared__ __align__(16) char h1s[64 * 256];   // 64 rows x 128 bf16 (256 B/row)
  const int tid  = threadIdx.x;
  const int wv   = tid >> 6;
  const int lane = tid & 63;
  const int r    = lane & 15;
  const int kb   = lane >> 4;
  const int row0 = blockIdx.x * 64 + wv * 16;

  const bf16x8* W1V = (const bf16x8*)W1f;
  const bf16x8* W2V = (const bf16x8*)W2f;

  // ---- phase 1: K=64, A = f32 feats ----
  f32x4 acc[8];
  #pragma unroll
  for (int c = 0; c < 8; ++c) acc[c] = (f32x4){0.f, 0.f, 0.f, 0.f};

  #pragma unroll
  for (int kt = 0; kt < 2; ++kt) {
    const int kofs = kt * 32 + kb * 8;
    int row = row0 + r; if (row >= n) row = n - 1;
    const float* fp = A + (size_t)row * 64 + kofs;
    float4 u = *(const float4*)fp;
    float4 v = *(const float4*)(fp + 4);
    bf16x8 a = (bf16x8){(bf16_t)u.x, (bf16_t)u.y, (bf16_t)u.z, (bf16_t)u.w,
                        (bf16_t)v.x, (bf16_t)v.y, (bf16_t)v.z, (bf16_t)v.w};
    #pragma unroll
    for (int c = 0; c < 8; ++c) {
      bf16x8 b = W1V[(kt * 8 + c) * 64 + lane];
      acc[c] = __builtin_amdgcn_mfma_f32_16x16x32_bf16(a, b, acc[c], 0, 0, 0);
    }
  }

  // epilogue 1: +b1, ELU, store bf16 to swizzled LDS (own wave's rows only)
  #pragma unroll
  for (int c = 0; c < 8; ++c) {
    const int col = c * 16 + r;
    const float bv = b1[col];
    #pragma unroll
    for (int q = 0; q < 4; ++q) {
      int rloc = wv * 16 + kb * 4 + q;
      float v = elu_fast(acc[c][q] + bv);
      int off = (rloc * 256 + col * 2) ^ ((rloc & 7) << 4);
      *(bf16_t*)(h1s + off) = (bf16_t)v;
    }
  }
  __syncthreads();

  // ---- phase 2: K=128, A from LDS ----
  #pragma unroll
  for (int c = 0; c < 8; ++c) acc[c] = (f32x4){0.f, 0.f, 0.f, 0.f};

  #pragma unroll
  for (int kt = 0; kt < 4; ++kt) {
    const int kbyte = (kt * 32 + kb * 8) * 2;
    int rloc = wv * 16 + r;
    int off = (rloc * 256 + kbyte) ^ ((rloc & 7) << 4);
    bf16x8 a = *(const bf16x8*)(h1s + off);
    #pragma unroll
    for (int c = 0; c < 8; ++c) {
      bf16x8 b = W2V[(kt * 8 + c) * 64 + lane];
      acc[c] = __builtin_amdgcn_mfma_f32_16x16x32_bf16(a, b, acc[c], 0, 0, 0);
    }
  }

  #pragma unroll
  for (int c = 0; c < 8; ++c) {
    const int col = c * 16 + r;
    const float bv = b2[col];
    #pragma unroll
    for (int q = 0; q < 4; ++q) {
      int row = row0 + kb * 4 + q;
      if (row < n) {
        float v = elu_fast(acc[c][q] + bv);
        outb[(size_t)row * 128 + col] = (bf16_t)v;
      }
    }
  }
}

// ---------------- MFMA dense (16 rows/wave, 64 rows/block) ----------------
// OMODE: 0 = bf16 out, 1 = f32 out, 2 = fp8 out (value * FP8_SCL)
template<int K1, int K2, bool DOELU, int OMODE, bool A2F32>
__global__ __launch_bounds__(256) void mf_dense(
    const bf16_t* __restrict__ A1, const bf16_t* __restrict__ A2b,
    const float* __restrict__ A2f,
    const bf16_t* __restrict__ Wf, const float* __restrict__ bias,
    bf16_t* __restrict__ outb, float* __restrict__ outf,
    unsigned char* __restrict__ outq, int n)
{
  constexpr int K   = K1 + K2;
  constexpr int NKT = K / 32;
  static_assert(K1 % 32 == 0, "K-step must not straddle A1/A2");

  const int tid  = threadIdx.x;
  const int wv   = tid >> 6;
  const int lane = tid & 63;
  const int r    = lane & 15;
  const int kb   = lane >> 4;
  const int row0 = blockIdx.x * 64 + wv * 16;

  f32x4 acc[8];
  #pragma unroll
  for (int c = 0; c < 8; ++c) acc[c] = (f32x4){0.f, 0.f, 0.f, 0.f};

  const bf16x8* WfV = (const bf16x8*)Wf;

  #pragma unroll
  for (int kt = 0; kt < NKT; ++kt) {
    const int kofs = kt * 32 + kb * 8;
    int row = row0 + r; if (row >= n) row = n - 1;
    bf16x8 a;
    if (K2 == 0 || kofs < K1) {
      a = *(const bf16x8*)(A1 + (size_t)row * K1 + kofs);
    } else if (A2F32) {
      const float* fp = A2f + (size_t)row * K2 + (kofs - K1);
      float4 u = *(const float4*)fp;
      float4 v = *(const float4*)(fp + 4);
      a = (bf16x8){(bf16_t)u.x, (bf16_t)u.y, (bf16_t)u.z, (bf16_t)u.w,
                   (bf16_t)v.x, (bf16_t)v.y, (bf16_t)v.z, (bf16_t)v.w};
    } else {
      a = *(const bf16x8*)(A2b + (size_t)row * K2 + (kofs - K1));
    }
    #pragma unroll
    for (int c = 0; c < 8; ++c) {
      bf16x8 b = WfV[(kt * 8 + c) * 64 + lane];
      acc[c] = __builtin_amdgcn_mfma_f32_16x16x32_bf16(a, b, acc[c], 0, 0, 0);
    }
  }

  #pragma unroll
  for (int c = 0; c < 8; ++c) {
    const int col = c * 16 + r;
    const float bv = bias ? bias[col] : 0.f;
    #pragma unroll
    for (int q = 0; q < 4; ++q) {
      int row = row0 + kb * 4 + q;
      if (row < n) {
        float v = acc[c][q] + bv;
        if (DOELU) v = elu_fast(v);
        if (OMODE == 0)      outb[(size_t)row * 128 + col] = (bf16_t)v;
        else if (OMODE == 1) outf[(size_t)row * 128 + col] = v;
        else                 outq[(size_t)row * 128 + col] = f_to_fp8(v * FP8_SCL);
      }
    }
  }
}

// ---------------- GCN aggregate v4: fp8 table, 128 B/row (one line) ----------------
__global__ __launch_bounds__(256) void gcn_agg4(
    const int* __restrict__ row_off, const int* __restrict__ csr,
    const float* __restrict__ dinv, const unsigned char* __restrict__ xq,
    const float* __restrict__ bgc, bf16_t* __restrict__ agg, int n)
{
  int w = (int)((blockIdx.x * (unsigned)blockDim.x + threadIdx.x) >> 6);
  if (w >= n) return;
  const int lane = threadIdx.x & 63;
  const int h  = lane >> 5;
  const int li = lane & 31;

  const float dd = dinv[w];
  f32x4 acc = (f32x4){0.f, 0.f, 0.f, 0.f};
  if (h == 0) {
    unsigned int sv = ((const unsigned int*)(xq + (size_t)w * 128))[li];
    fp8x4_fma(acc, sv, dd);
  }

  const int e0 = row_off[w], e1 = row_off[w + 1];
  int e = e0;
  for (; e + 8 <= e1; e += 8) {
    #pragma unroll
    for (int u = 0; u < 4; ++u) {
      int s = csr[e + 2 * u + h];
      float ds = dinv[s];
      unsigned int v = ((const unsigned int*)(xq + (size_t)s * 128))[li];
      fp8x4_fma(acc, v, ds);
    }
  }
  for (; e < e1; e += 2) {
    int idx = e + h;
    int cidx = idx < e1 ? idx : e1 - 1;
    int s = csr[cidx];
    float ds = idx < e1 ? dinv[s] : 0.f;
    unsigned int v = ((const unsigned int*)(xq + (size_t)s * 128))[li];
    fp8x4_fma(acc, v, ds);
  }

  #pragma unroll
  for (int j = 0; j < 4; ++j) acc[j] += __shfl_xor(acc[j], 32);

  if (h == 0) {
    const float sc = dd * FP8_ISCL;
    f32x4 bb = ((const f32x4*)bgc)[li];
    bf16x4 o;
    o[0] = (bf16_t)(acc[0] * sc + bb[0]); o[1] = (bf16_t)(acc[1] * sc + bb[1]);
    o[2] = (bf16_t)(acc[2] * sc + bb[2]); o[3] = (bf16_t)(acc[3] * sc + bb[3]);
    ((bf16x4*)(agg + (size_t)w * 128))[li] = o;
  }
}

// ---------------- launch ----------------

extern "C" void kernel_launch(void* const* d_in, const int* in_sizes, int n_in,
                              void* d_out, int out_size, void* d_ws, size_t ws_size,
                              hipStream_t stream) {
  (void)in_sizes; (void)n_in; (void)out_size; (void)ws_size;
  const float* feats = (const float*)d_in[0];
  const int*   edges = (const int*)d_in[1];
  const int*   batch = (const int*)d_in[2];
  const float* W1  = (const float*)d_in[3];
  const float* b1  = (const float*)d_in[4];
  const float* W2  = (const float*)d_in[5];
  const float* b2  = (const float*)d_in[6];
  const float* Wgc = (const float*)d_in[7];
  const float* bgc = (const float*)d_in[8];
  const float* Wc  = (const float*)d_in[9];
  const float* bc  = (const float*)d_in[10];
  float* out = (float*)d_out;

  // workspace layout
  bf16_t* h2b  = (bf16_t*)d_ws;                      // [NN*128] bf16 (nfeats)
  bf16_t* aggb = h2b  + (size_t)NN * 128;            // [NN*128] bf16
  unsigned char* xq8 = (unsigned char*)(aggb + (size_t)NN * 128);  // [NN*128] fp8
  float*  dinv = (float*)(xq8 + (size_t)NN * 128);   // [NN]
  bf16_t* wall = (bf16_t*)(dinv + NN);               // [81920] frag-ordered Ws
  bf16_t* w1f  = wall;
  bf16_t* w2f  = wall + 8192;
  bf16_t* wgcf = wall + 24576;
  bf16_t* wcf  = wall + 49152;

  // scratch in the FRONT of d_out (dead before final mf_dense writes it)
  int* scr     = (int*)d_out;
  int* csr_src = scr;                   // [NE]
  int* row_off = csr_src + NE;          // [NN+1]
  int* H       = row_off + NN + 1;      // [NH]
  int* Hincl   = H + NH;                // [NH]
  int* Hoff    = Hincl + NH;            // [NH+1]
  int* boff    = Hoff + NH + 1;         // [NB1+1]
  int* bsum2   = boff + NB1 + 1;        // [512]
  unsigned long long* ebuf =
      (unsigned long long*)(((uintptr_t)(bsum2 + 512) + 7) & ~(uintptr_t)7);  // [NE]

  const int* esrc = edges;
  const int* edst = edges + NE;

  const int nscH = (NH + SB - 1) / SB;   // 151

  // --- CSR build: block-owned bucket sort + fused finalize ---
  histA   <<<NBLK, 256, 0, stream>>>(edst, H, NE);
  scan_blk<<<nscH, SB, 0, stream>>>(H, Hincl, bsum2, NH);
  scan_top<<<1, 512, 0, stream>>>(bsum2, nscH);
  scan_add<<<nscH, SB, 0, stream>>>(Hincl, H, bsum2, Hoff, NH);
  boff_k  <<<1, 256, 0, stream>>>(Hoff, boff);
  scatterA<<<NBLK, 256, 0, stream>>>(esrc, edst, Hoff, ebuf, NE);
  bfin    <<<NB1, 512, 0, stream>>>(ebuf, boff, row_off, dinv, csr_src, NN);

  // --- weight prep (single launch) ---
  wprep4<<<320, 256, 0, stream>>>(W1, W2, Wgc, Wc, wall);

  // --- dense chain on MFMA (64 rows/block, 16 rows/wave) ---
  const int nb = (NN + 63) / 64;   // 1563
  mf_dense12<<<nb, 256, 0, stream>>>(feats, w1f, b1, w2f, b2, h2b, NN);
  // GCN linear layer -> fp8 table (scaled x128)
  mf_dense<128, 64, false, 2, true><<<nb, 256, 0, stream>>>(
      h2b, nullptr, feats, wgcf, nullptr, nullptr, nullptr, xq8, NN);

  // --- GCN aggregate (fp8 gather) ---
  long long wthreads = (long long)NN * 64;
  gcn_agg4<<<(int)((wthreads + 255) / 256), 256, 0, stream>>>(
      row_off, csr_src, dinv, xq8, bgc, aggb, NN);

  // --- output layer (fp32 into d_out, overwrites scratch) ---
  mf_dense<128, 128, true, 1, false><<<nb, 256, 0, stream>>>(
      h2b, aggb, nullptr, wcf, bc, nullptr, out, nullptr, NN);

  // tail outputs: edges and batch, as float
  size_t off = (size_t)NN * 128;
  i2f_k<<<(2 * NE + 255) / 256, 256, 0, stream>>>(edges, out + off, 2 * NE);
  i2f_k<<<(NN + 255) / 256, 256, 0, stream>>>(batch, out + off + (size_t)2 * NE, NN);
}

// Round 12
// 205.537 us; speedup vs baseline: 3.7547x; 1.0478x over previous
//
#include <hip/hip_runtime.h>
#include <hip/hip_bf16.h>
#include <hip/hip_fp8.h>

constexpr int NN = 100000;
constexpr int NE = 1600000;

constexpr int SH1  = 9;                      // 512 nodes per bucket
constexpr int NB1  = (NN + 511) >> SH1;      // 196 buckets
constexpr int EB   = 8192;                   // edges per pass-A block
constexpr int NBLK = (NE + EB - 1) / EB;     // 196 blocks
constexpr int NH   = NB1 * NBLK;             // 38416 histogram cells

constexpr float FP8_SCL  = 128.f;
constexpr float FP8_ISCL = 1.f / 128.f;

typedef __bf16 bf16_t;
typedef bf16_t bf16x8 __attribute__((ext_vector_type(8)));
typedef bf16_t bf16x4 __attribute__((ext_vector_type(4)));
typedef float  f32x4  __attribute__((ext_vector_type(4)));

// fast ELU: exp via v_exp_f32 (HW transcendental), ~1e-5 rel err vs expm1f
__device__ inline float elu_fast(float v) {
  return v > 0.f ? v : (__expf(v) - 1.f);
}

// fp8 helpers (sel must be a literal -> template parameter)
__device__ inline unsigned char f_to_fp8(float v) {
  __hip_fp8_e4m3 q(v);
  return q.__x;
}
template<int SEL>
__device__ inline float fp8_to_f(unsigned int word) {
#if __has_builtin(__builtin_amdgcn_cvt_f32_fp8)
  return __builtin_amdgcn_cvt_f32_fp8(word, SEL);
#else
  __hip_fp8_e4m3 t; t.__x = (word >> (8 * SEL)) & 0xff; return (float)t;
#endif
}
// decode 8 packed fp8 (uint2) and FMA into acc[8] with scale
__device__ inline void fp8x8_fma(float* acc, uint2 v, float s) {
  acc[0] += fp8_to_f<0>(v.x) * s;
  acc[1] += fp8_to_f<1>(v.x) * s;
  acc[2] += fp8_to_f<2>(v.x) * s;
  acc[3] += fp8_to_f<3>(v.x) * s;
  acc[4] += fp8_to_f<0>(v.y) * s;
  acc[5] += fp8_to_f<1>(v.y) * s;
  acc[6] += fp8_to_f<2>(v.y) * s;
  acc[7] += fp8_to_f<3>(v.y) * s;
}

// ---------------- generic scan chain (used for H only) ----------------
constexpr int SB = 256;

__global__ void scan_blk(const int* __restrict__ in, int* __restrict__ incl,
                         int* __restrict__ bsum, int n) {
  __shared__ int sm[SB];
  int i = blockIdx.x * SB + threadIdx.x;
  int v = (i < n) ? in[i] : 0;
  sm[threadIdx.x] = v;
  __syncthreads();
  for (int off = 1; off < SB; off <<= 1) {
    int t = (threadIdx.x >= off) ? sm[threadIdx.x - off] : 0;
    __syncthreads();
    sm[threadIdx.x] += t;
    __syncthreads();
  }
  if (i < n) incl[i] = sm[threadIdx.x];
  if (threadIdx.x == SB - 1) bsum[blockIdx.x] = sm[SB - 1];
}

__global__ void scan_top(int* __restrict__ bsum, int nb) {
  __shared__ int sm[512];
  int t = threadIdx.x;
  int v = (t < nb) ? bsum[t] : 0;
  sm[t] = v;
  __syncthreads();
  for (int off = 1; off < 512; off <<= 1) {
    int u = (t >= off) ? sm[t - off] : 0;
    __syncthreads();
    sm[t] += u;
    __syncthreads();
  }
  if (t < nb) bsum[t] = sm[t] - v;   // exclusive
}

__global__ void scan_add(const int* __restrict__ incl, const int* __restrict__ in,
                         const int* __restrict__ bsum, int* __restrict__ outoff, int n) {
  int i = blockIdx.x * SB + threadIdx.x;
  if (i < n) {
    int off = bsum[blockIdx.x];
    outoff[i] = off + incl[i] - in[i];    // exclusive prefix
    if (i == n - 1) outoff[n] = off + incl[i];
  }
}

// ---------------- pass A: block-local histogram + owned-range scatter ----------------

__global__ __launch_bounds__(256) void histA(const int* __restrict__ dst,
                                             int* __restrict__ H, int e) {
  __shared__ int h[NB1];
  for (int i = threadIdx.x; i < NB1; i += 256) h[i] = 0;
  __syncthreads();
  int base = blockIdx.x * EB;
  int end = min(base + EB, e);
  for (int i = base + threadIdx.x; i < end; i += 256)
    atomicAdd(&h[dst[i] >> SH1], 1);
  __syncthreads();
  for (int i = threadIdx.x; i < NB1; i += 256)
    H[i * NBLK + blockIdx.x] = h[i];
}

__global__ void boff_k(const int* __restrict__ Hoff, int* __restrict__ boff) {
  int i = blockIdx.x * blockDim.x + threadIdx.x;
  if (i < NB1) boff[i] = Hoff[i * NBLK];
  if (i == NB1) boff[NB1] = NE;
}

__global__ __launch_bounds__(256) void scatterA(
    const int* __restrict__ src, const int* __restrict__ dst,
    const int* __restrict__ Hoff, unsigned long long* __restrict__ ebuf, int e) {
  __shared__ int cur[NB1];
  for (int i = threadIdx.x; i < NB1; i += 256)
    cur[i] = Hoff[i * NBLK + blockIdx.x];
  __syncthreads();
  int base = blockIdx.x * EB;
  int end = min(base + EB, e);
  for (int i = base + threadIdx.x; i < end; i += 256) {
    int d = dst[i], s = src[i];
    int pos = atomicAdd(&cur[d >> SH1], 1);
    ebuf[pos] = ((unsigned long long)(unsigned)d << 32) | (unsigned)s;
  }
}

// ---------------- pass B fused: degree + scan + row_off + dinv + placement ----------------

__global__ __launch_bounds__(512) void bfin(const unsigned long long* __restrict__ ebuf,
                                            const int* __restrict__ boff,
                                            int* __restrict__ row_off, float* __restrict__ dinv,
                                            int* __restrict__ csr, int n) {
  __shared__ int cnt[512];
  __shared__ int loc[512];
  const int tid = threadIdx.x;
  const int b = blockIdx.x;
  cnt[tid] = 0;
  __syncthreads();
  const int e0 = boff[b], e1 = boff[b + 1];
  for (int e = e0 + tid; e < e1; e += 512)
    atomicAdd(&cnt[(int)(ebuf[e] >> 32) & 511], 1);
  __syncthreads();
  loc[tid] = cnt[tid];
  __syncthreads();
  for (int off = 1; off < 512; off <<= 1) {
    int t = (tid >= off) ? loc[tid - off] : 0;
    __syncthreads();
    loc[tid] += t;
    __syncthreads();
  }
  const int excl = loc[tid] - cnt[tid];
  const int node = (b << SH1) + tid;
  if (node < n) {
    row_off[node] = boff[b] + excl;
    dinv[node] = rsqrtf((float)cnt[tid] + 1.0f);   // +1 self-loop
  }
  if (b == NB1 - 1 && tid == 0) row_off[n] = NE;
  cnt[tid] = boff[b] + excl;
  __syncthreads();
  for (int e = e0 + tid; e < e1; e += 512) {
    unsigned long long v = ebuf[e];
    int dl = (int)(v >> 32) & 511;
    int s  = (int)(v & 0xffffffffu);
    int slot = atomicAdd(&cnt[dl], 1);
    csr[slot] = s;
  }
}

// ---------------- misc ----------------

__global__ void i2f_k(const int* __restrict__ in, float* __restrict__ out, int n) {
  int i = blockIdx.x * blockDim.x + threadIdx.x;
  if (i < n) out[i] = (float)in[i];
}

// all four weight shuffles in one launch. grid = 320*256 = 81920 exactly.
__global__ void wprep4(const float* __restrict__ W1, const float* __restrict__ W2,
                       const float* __restrict__ Wgc, const float* __restrict__ Wc,
                       bf16_t* __restrict__ Wf) {
  int idx = blockIdx.x * blockDim.x + threadIdx.x;
  const float* W; int base;
  if      (idx < 8192)  { W = W1;  base = 0; }
  else if (idx < 24576) { W = W2;  base = 8192; }
  else if (idx < 49152) { W = Wgc; base = 24576; }
  else                  { W = Wc;  base = 49152; }
  int il   = idx - base;
  int j    = il & 7;
  int lane = (il >> 3) & 63;
  int c    = (il >> 9) & 7;
  int kt   = il >> 12;
  int k    = kt * 32 + (lane >> 4) * 8 + j;
  int col  = c * 16 + (lane & 15);
  Wf[idx] = (bf16_t)W[(size_t)k * 128 + col];
}

// ---------------- fused dense layers 1+2+GCN-linear (16 rows/wave) ----------------
// h2 = elu( elu(feats@W1+b1) @ W2 + b2 )         -> h2out (bf16)
// xq = (concat(h2, feats) @ Wgc) * FP8_SCL       -> xqout (fp8)
// Each wave owns its 16 rows end-to-end; LDS rows are wave-private -> NO barriers.
__global__ __launch_bounds__(256) void mf_dense123(
    const float* __restrict__ A, const bf16_t* __restrict__ W1f, const float* __restrict__ b1,
    const bf16_t* __restrict__ W2f, const float* __restrict__ b2,
    const bf16_t* __restrict__ Wgf,
    bf16_t* __restrict__ h2out, unsigned char* __restrict__ xqout, int n)
{
  __shared__ __align__(16) char h1s[64 * 256];   // 64 rows x 128 bf16 (256 B/row), wave-private rows
  const int tid  = threadIdx.x;
  const int wv   = tid >> 6;
  const int lane = tid & 63;
  const int r    = lane & 15;
  const int kb   = lane >> 4;
  const int row0 = blockIdx.x * 64 + wv * 16;

  const bf16x8* W1V = (const bf16x8*)W1f;
  const bf16x8* W2V = (const bf16x8*)W2f;
  const bf16x8* WgV = (const bf16x8*)Wgf;

  // ---- phase 1: K=64, A = f32 feats ----
  f32x4 acc[8];
  #pragma unroll
  for (int c = 0; c < 8; ++c) acc[c] = (f32x4){0.f, 0.f, 0.f, 0.f};

  #pragma unroll
  for (int kt = 0; kt < 2; ++kt) {
    const int kofs = kt * 32 + kb * 8;
    int row = row0 + r; if (row >= n) row = n - 1;
    const float* fp = A + (size_t)row * 64 + kofs;
    float4 u = *(const float4*)fp;
    float4 v = *(const float4*)(fp + 4);
    bf16x8 a = (bf16x8){(bf16_t)u.x, (bf16_t)u.y, (bf16_t)u.z, (bf16_t)u.w,
                        (bf16_t)v.x, (bf16_t)v.y, (bf16_t)v.z, (bf16_t)v.w};
    #pragma unroll
    for (int c = 0; c < 8; ++c) {
      bf16x8 b = W1V[(kt * 8 + c) * 64 + lane];
      acc[c] = __builtin_amdgcn_mfma_f32_16x16x32_bf16(a, b, acc[c], 0, 0, 0);
    }
  }

  // epilogue 1: +b1, ELU, store bf16 to swizzled LDS (own wave's rows only)
  #pragma unroll
  for (int c = 0; c < 8; ++c) {
    const int col = c * 16 + r;
    const float bv = b1[col];
    #pragma unroll
    for (int q = 0; q < 4; ++q) {
      int rloc = wv * 16 + kb * 4 + q;
      float v = elu_fast(acc[c][q] + bv);
      int off = (rloc * 256 + col * 2) ^ ((rloc & 7) << 4);
      *(bf16_t*)(h1s + off) = (bf16_t)v;
    }
  }

  // ---- phase 2: K=128, A = h1 from LDS ----
  #pragma unroll
  for (int c = 0; c < 8; ++c) acc[c] = (f32x4){0.f, 0.f, 0.f, 0.f};

  #pragma unroll
  for (int kt = 0; kt < 4; ++kt) {
    const int kbyte = (kt * 32 + kb * 8) * 2;
    int rloc = wv * 16 + r;
    int off = (rloc * 256 + kbyte) ^ ((rloc & 7) << 4);
    bf16x8 a = *(const bf16x8*)(h1s + off);
    #pragma unroll
    for (int c = 0; c < 8; ++c) {
      bf16x8 b = W2V[(kt * 8 + c) * 64 + lane];
      acc[c] = __builtin_amdgcn_mfma_f32_16x16x32_bf16(a, b, acc[c], 0, 0, 0);
    }
  }

  // epilogue 2: h2 = elu(acc+b2); write global h2out AND re-stage into LDS (h1 slot, dead now)
  #pragma unroll
  for (int c = 0; c < 8; ++c) {
    const int col = c * 16 + r;
    const float bv = b2[col];
    #pragma unroll
    for (int q = 0; q < 4; ++q) {
      int row  = row0 + kb * 4 + q;
      int rloc = wv * 16 + kb * 4 + q;
      float v = elu_fast(acc[c][q] + bv);
      int off = (rloc * 256 + col * 2) ^ ((rloc & 7) << 4);
      *(bf16_t*)(h1s + off) = (bf16_t)v;
      if (row < n) h2out[(size_t)row * 128 + col] = (bf16_t)v;
    }
  }

  // ---- phase 3: K=192 (h2 from LDS ++ feats from global), -> fp8 table ----
  #pragma unroll
  for (int c = 0; c < 8; ++c) acc[c] = (f32x4){0.f, 0.f, 0.f, 0.f};

  #pragma unroll
  for (int kt = 0; kt < 6; ++kt) {
    const int kofs = kt * 32 + kb * 8;
    bf16x8 a;
    if (kofs < 128) {
      int rloc = wv * 16 + r;
      int off = (rloc * 256 + kofs * 2) ^ ((rloc & 7) << 4);
      a = *(const bf16x8*)(h1s + off);
    } else {
      int row = row0 + r; if (row >= n) row = n - 1;
      const float* fp = A + (size_t)row * 64 + (kofs - 128);
      float4 u = *(const float4*)fp;
      float4 v = *(const float4*)(fp + 4);
      a = (bf16x8){(bf16_t)u.x, (bf16_t)u.y, (bf16_t)u.z, (bf16_t)u.w,
                   (bf16_t)v.x, (bf16_t)v.y, (bf16_t)v.z, (bf16_t)v.w};
    }
    #pragma unroll
    for (int c = 0; c < 8; ++c) {
      bf16x8 b = WgV[(kt * 8 + c) * 64 + lane];
      acc[c] = __builtin_amdgcn_mfma_f32_16x16x32_bf16(a, b, acc[c], 0, 0, 0);
    }
  }

  // epilogue 3: no bias, no ELU; fp8 out scaled x128
  #pragma unroll
  for (int c = 0; c < 8; ++c) {
    const int col = c * 16 + r;
    #pragma unroll
    for (int q = 0; q < 4; ++q) {
      int row = row0 + kb * 4 + q;
      if (row < n)
        xqout[(size_t)row * 128 + col] = f_to_fp8(acc[c][q] * FP8_SCL);
    }
  }
}

// ---------------- MFMA dense (16 rows/wave) — final output layer ----------------
template<int K1, int K2, bool DOELU, int OMODE>
__global__ __launch_bounds__(256) void mf_dense(
    const bf16_t* __restrict__ A1, const bf16_t* __restrict__ A2b,
    const bf16_t* __restrict__ Wf, const float* __restrict__ bias,
    bf16_t* __restrict__ outb, float* __restrict__ outf, int n)
{
  constexpr int K   = K1 + K2;
  constexpr int NKT = K / 32;

  const int tid  = threadIdx.x;
  const int wv   = tid >> 6;
  const int lane = tid & 63;
  const int r    = lane & 15;
  const int kb   = lane >> 4;
  const int row0 = blockIdx.x * 64 + wv * 16;

  f32x4 acc[8];
  #pragma unroll
  for (int c = 0; c < 8; ++c) acc[c] = (f32x4){0.f, 0.f, 0.f, 0.f};

  const bf16x8* WfV = (const bf16x8*)Wf;

  #pragma unroll
  for (int kt = 0; kt < NKT; ++kt) {
    const int kofs = kt * 32 + kb * 8;
    int row = row0 + r; if (row >= n) row = n - 1;
    bf16x8 a;
    if (kofs < K1) a = *(const bf16x8*)(A1 + (size_t)row * K1 + kofs);
    else           a = *(const bf16x8*)(A2b + (size_t)row * K2 + (kofs - K1));
    #pragma unroll
    for (int c = 0; c < 8; ++c) {
      bf16x8 b = WfV[(kt * 8 + c) * 64 + lane];
      acc[c] = __builtin_amdgcn_mfma_f32_16x16x32_bf16(a, b, acc[c], 0, 0, 0);
    }
  }

  #pragma unroll
  for (int c = 0; c < 8; ++c) {
    const int col = c * 16 + r;
    const float bv = bias ? bias[col] : 0.f;
    #pragma unroll
    for (int q = 0; q < 4; ++q) {
      int row = row0 + kb * 4 + q;
      if (row < n) {
        float v = acc[c][q] + bv;
        if (DOELU) v = elu_fast(v);
        if (OMODE == 0) outb[(size_t)row * 128 + col] = (bf16_t)v;
        else            outf[(size_t)row * 128 + col] = v;
      }
    }
  }
}

// ---------------- GCN aggregate v5: fp8 table, 4 edges/wave (16-lane groups) ----------------
// agg[d] = dinv[d] * ( sum_s xq[s]*dinv[s] + xq[d]*dinv[d] ) / FP8_SCL + bgc
__global__ __launch_bounds__(256) void gcn_agg5(
    const int* __restrict__ row_off, const int* __restrict__ csr,
    const float* __restrict__ dinv, const unsigned char* __restrict__ xq,
    const float* __restrict__ bgc, bf16_t* __restrict__ agg, int n)
{
  int w = (int)((blockIdx.x * (unsigned)blockDim.x + threadIdx.x) >> 6);
  if (w >= n) return;
  const int lane = threadIdx.x & 63;
  const int g  = lane >> 4;     // edge subgroup 0..3
  const int li = lane & 15;     // feature octet: cols 8*li .. 8*li+7

  const float dd = dinv[w];
  float acc[8];
  #pragma unroll
  for (int j = 0; j < 8; ++j) acc[j] = 0.f;

  if (g == 0) {
    uint2 sv = ((const uint2*)(xq + (size_t)w * 128))[li];
    fp8x8_fma(acc, sv, dd);     // self-loop term
  }

  const int e0 = row_off[w], e1 = row_off[w + 1];
  int e = e0;
  for (; e + 16 <= e1; e += 16) {
    #pragma unroll
    for (int u = 0; u < 4; ++u) {
      int s = csr[e + 4 * u + g];
      float ds = dinv[s];
      uint2 v = ((const uint2*)(xq + (size_t)s * 128))[li];
      fp8x8_fma(acc, v, ds);
    }
  }
  for (; e < e1; e += 4) {
    int idx = e + g;
    int cidx = idx < e1 ? idx : e1 - 1;
    int s = csr[cidx];
    float ds = idx < e1 ? dinv[s] : 0.f;
    uint2 v = ((const uint2*)(xq + (size_t)s * 128))[li];
    fp8x8_fma(acc, v, ds);
  }

  #pragma unroll
  for (int j = 0; j < 8; ++j) {
    acc[j] += __shfl_xor(acc[j], 16);
    acc[j] += __shfl_xor(acc[j], 32);
  }

  if (g == 0) {
    const float sc = dd * FP8_ISCL;
    f32x4 b0 = ((const f32x4*)bgc)[2 * li];
    f32x4 b1 = ((const f32x4*)bgc)[2 * li + 1];
    bf16x8 o;
    o[0] = (bf16_t)(acc[0] * sc + b0[0]); o[1] = (bf16_t)(acc[1] * sc + b0[1]);
    o[2] = (bf16_t)(acc[2] * sc + b0[2]); o[3] = (bf16_t)(acc[3] * sc + b0[3]);
    o[4] = (bf16_t)(acc[4] * sc + b1[0]); o[5] = (bf16_t)(acc[5] * sc + b1[1]);
    o[6] = (bf16_t)(acc[6] * sc + b1[2]); o[7] = (bf16_t)(acc[7] * sc + b1[3]);
    ((bf16x8*)(agg + (size_t)w * 128))[li] = o;
  }
}

// ---------------- launch ----------------

extern "C" void kernel_launch(void* const* d_in, const int* in_sizes, int n_in,
                              void* d_out, int out_size, void* d_ws, size_t ws_size,
                              hipStream_t stream) {
  (void)in_sizes; (void)n_in; (void)out_size; (void)ws_size;
  const float* feats = (const float*)d_in[0];
  const int*   edges = (const int*)d_in[1];
  const int*   batch = (const int*)d_in[2];
  const float* W1  = (const float*)d_in[3];
  const float* b1  = (const float*)d_in[4];
  const float* W2  = (const float*)d_in[5];
  const float* b2  = (const float*)d_in[6];
  const float* Wgc = (const float*)d_in[7];
  const float* bgc = (const float*)d_in[8];
  const float* Wc  = (const float*)d_in[9];
  const float* bc  = (const float*)d_in[10];
  float* out = (float*)d_out;

  // workspace layout
  bf16_t* h2b  = (bf16_t*)d_ws;                      // [NN*128] bf16 (nfeats)
  bf16_t* aggb = h2b  + (size_t)NN * 128;            // [NN*128] bf16
  unsigned char* xq8 = (unsigned char*)(aggb + (size_t)NN * 128);  // [NN*128] fp8
  float*  dinv = (float*)(xq8 + (size_t)NN * 128);   // [NN]
  bf16_t* wall = (bf16_t*)(dinv + NN);               // [81920] frag-ordered Ws
  bf16_t* w1f  = wall;
  bf16_t* w2f  = wall + 8192;
  bf16_t* wgcf = wall + 24576;
  bf16_t* wcf  = wall + 49152;

  // scratch in the FRONT of d_out (dead before final mf_dense writes it)
  int* scr     = (int*)d_out;
  int* csr_src = scr;                   // [NE]
  int* row_off = csr_src + NE;          // [NN+1]
  int* H       = row_off + NN + 1;      // [NH]
  int* Hincl   = H + NH;                // [NH]
  int* Hoff    = Hincl + NH;            // [NH+1]
  int* boff    = Hoff + NH + 1;         // [NB1+1]
  int* bsum2   = boff + NB1 + 1;        // [512]
  unsigned long long* ebuf =
      (unsigned long long*)(((uintptr_t)(bsum2 + 512) + 7) & ~(uintptr_t)7);  // [NE]

  const int* esrc = edges;
  const int* edst = edges + NE;

  const int nscH = (NH + SB - 1) / SB;   // 151

  // --- CSR build: block-owned bucket sort + fused finalize ---
  histA   <<<NBLK, 256, 0, stream>>>(edst, H, NE);
  scan_blk<<<nscH, SB, 0, stream>>>(H, Hincl, bsum2, NH);
  scan_top<<<1, 512, 0, stream>>>(bsum2, nscH);
  scan_add<<<nscH, SB, 0, stream>>>(Hincl, H, bsum2, Hoff, NH);
  boff_k  <<<1, 256, 0, stream>>>(Hoff, boff);
  scatterA<<<NBLK, 256, 0, stream>>>(esrc, edst, Hoff, ebuf, NE);
  bfin    <<<NB1, 512, 0, stream>>>(ebuf, boff, row_off, dinv, csr_src, NN);

  // --- weight prep (single launch) ---
  wprep4<<<320, 256, 0, stream>>>(W1, W2, Wgc, Wc, wall);

  // --- fused dense 1+2+GCN-linear (64 rows/block, 16 rows/wave) ---
  const int nb = (NN + 63) / 64;   // 1563
  mf_dense123<<<nb, 256, 0, stream>>>(feats, w1f, b1, w2f, b2, wgcf, h2b, xq8, NN);

  // --- GCN aggregate (fp8 gather, 4 edges/wave) ---
  long long wthreads = (long long)NN * 64;
  gcn_agg5<<<(int)((wthreads + 255) / 256), 256, 0, stream>>>(
      row_off, csr_src, dinv, xq8, bgc, aggb, NN);

  // --- output layer (fp32 into d_out, overwrites scratch) ---
  mf_dense<128, 128, true, 1><<<nb, 256, 0, stream>>>(
      h2b, aggb, wcf, bc, nullptr, out, NN);

  // tail outputs: edges and batch, as float
  size_t off = (size_t)NN * 128;
  i2f_k<<<(2 * NE + 255) / 256, 256, 0, stream>>>(edges, out + off, 2 * NE);
  i2f_k<<<(NN + 255) / 256, 256, 0, stream>>>(batch, out + off + (size_t)2 * NE, NN);
}